// Round 16
// baseline (160.216 us; speedup 1.0000x reference)
//
#include <hip/hip_runtime.h>
#include <hip/hip_bf16.h>
#include <hip/hip_fp16.h>

typedef __hip_bfloat16 bf16;
typedef __attribute__((ext_vector_type(8))) short short8;
typedef __attribute__((ext_vector_type(4))) float f32x4;
typedef __attribute__((ext_vector_type(16))) float f32x16;

#define MFMA(a, b, c) __builtin_amdgcn_mfma_f32_16x16x32_bf16((a), (b), (c), 0, 0, 0)
#define MFMA32(a, b, c) __builtin_amdgcn_mfma_f32_32x32x16_bf16((a), (b), (c), 0, 0, 0)
#define SPLIT 2

// ---------------------------------------------------------------------------
// Mask element-size detection. flag=0 -> 4-byte elements, flag=1 -> 1-byte.
// ---------------------------------------------------------------------------
__global__ void detect_mask(const unsigned int* __restrict__ m, int* __restrict__ flag)
{
    __shared__ int bad;
    if (threadIdx.x == 0) bad = 0;
    __syncthreads();
    unsigned int w = m[threadIdx.x];
    bool ok = (w == 0u) || (w == 1u) || (w == 0x3F800000u);
    if (!ok) atomicAdd(&bad, 1);
    __syncthreads();
    if (threadIdx.x == 0) *flag = (bad == 0) ? 0 : 1;
}

// ---------------------------------------------------------------------------
// MLP folding: W_eff = W3*W2*W1, b_eff = W3*(W2*b1+b2)+b3.
// Q head gets rsqrt(128)*log2(e) folded in.
// ---------------------------------------------------------------------------
__global__ void compose_a(const float* __restrict__ qw, const float* __restrict__ qb,
                          const float* __restrict__ kw, const float* __restrict__ kb,
                          const float* __restrict__ vw, const float* __restrict__ vb,
                          float* __restrict__ T, float* __restrict__ bt)
{
    int h = blockIdx.x >> 7;
    int i = blockIdx.x & 127;
    int j = threadIdx.x;
    const float* W = (h == 0) ? qw : (h == 1) ? kw : vw;
    const float* bv = (h == 0) ? qb : (h == 1) ? kb : vb;
    const float* W1 = W;
    const float* W2 = W + 128 * 128;
    float acc = 0.f;
    for (int k = 0; k < 128; ++k) acc += W2[i * 128 + k] * W1[k * 128 + j];
    T[h * 16384 + i * 128 + j] = acc;
    if (j == 0) {
        float bacc = 0.f;
        for (int k = 0; k < 128; ++k) bacc += W2[i * 128 + k] * bv[k];
        bt[h * 128 + i] = bacc + bv[128 + i];
    }
}

__global__ void compose_b(const float* __restrict__ qw, const float* __restrict__ qb,
                          const float* __restrict__ kw, const float* __restrict__ kb,
                          const float* __restrict__ vw, const float* __restrict__ vb,
                          const float* __restrict__ T, const float* __restrict__ bt,
                          bf16* __restrict__ Weff, float* __restrict__ beff)
{
    int h = blockIdx.x >> 7;
    int i = blockIdx.x & 127;
    int j = threadIdx.x;
    const float* W = (h == 0) ? qw : (h == 1) ? kw : vw;
    const float* bv = (h == 0) ? qb : (h == 1) ? kb : vb;
    const float* W3 = W + 2 * 128 * 128;
    const float* Th = T + h * 16384;
    float acc = 0.f;
    for (int k = 0; k < 128; ++k) acc += W3[i * 128 + k] * Th[k * 128 + j];
    float scale = (h == 0) ? (1.4426950408889634f * rsqrtf(128.0f)) : 1.0f;
    Weff[h * 16384 + i * 128 + j] = __float2bfloat16(acc * scale);
    if (j == 0) {
        float bacc = 0.f;
        for (int k = 0; k < 128; ++k) bacc += W3[i * 128 + k] * bt[h * 128 + k];
        beff[h * 128 + i] = (bacc + bv[256 + i]) * scale;
    }
}

// ---------------------------------------------------------------------------
// Q projection, row-major output: Y[r][w] = sum_c X[r][c]*W[w][c] + bias[w]
// ---------------------------------------------------------------------------
__global__ __launch_bounds__(256) void proj_rm(
    const float* __restrict__ X, const bf16* __restrict__ Wb,
    const float* __restrict__ bias, bf16* __restrict__ Y)
{
    __shared__ alignas(16) char sX[64 * 256];
    int tid = threadIdx.x;
    int lane = tid & 63, wave = tid >> 6;
    int l16 = lane & 15, lhi = lane >> 4;
    long long r0 = (long long)blockIdx.x * 64;
    {
        int row = tid >> 2, seg = tid & 3;
        const float4* src = reinterpret_cast<const float4*>(X + (r0 + row) * 128 + seg * 32);
        int swz = (row & 7) << 4;
        char* dst0 = &sX[0] + row * 256;
#pragma unroll
        for (int i = 0; i < 8; ++i) {
            float4 v = src[i];
            bf16* d = (bf16*)(dst0 + ((seg * 64 + i * 8) ^ swz));
            d[0] = __float2bfloat16(v.x); d[1] = __float2bfloat16(v.y);
            d[2] = __float2bfloat16(v.z); d[3] = __float2bfloat16(v.w);
        }
    }
    __syncthreads();
    int rloc = wave * 16 + l16;
    int swzr = (rloc & 7) << 4;
    short8 a[4];
#pragma unroll
    for (int c4 = 0; c4 < 4; ++c4)
        a[c4] = *(const short8*)(&sX[0] + ((rloc * 256 + lhi * 16 + c4 * 64) ^ swzr));
    f32x4 acc[8] = {};
#pragma unroll
    for (int n = 0; n < 8; ++n) {
        const bf16* wr = Wb + (n * 16 + l16) * 128 + lhi * 8;
#pragma unroll
        for (int c4 = 0; c4 < 4; ++c4)
            acc[n] = MFMA(a[c4], *(const short8*)(wr + c4 * 32), acc[n]);
    }
#pragma unroll
    for (int n = 0; n < 8; ++n) {
        float bia = bias[l16 + 16 * n];
#pragma unroll
        for (int r = 0; r < 4; ++r) {
            long long q = r0 + wave * 16 + lhi * 4 + r;
            Y[q * 128 + l16 + 16 * n] = __float2bfloat16(acc[n][r] + bia);
        }
    }
}

// ---------------------------------------------------------------------------
// FUSED K+V projection. Emission layouts for the 32x32x16 attention path:
//  Kf frag(t32, f):  K[t32*32 + (l&31)][f*16 + (l>>5)*8 + 0..7]   (A operand)
//  Vf frag(t32, kvh, wc): V[t32*32 + kvh*16 + (l>>5)*8 + 0..7][wc*32 + (l&31)]
// Each frag is a coalesced 1KB burst (lane*16B).
// ---------------------------------------------------------------------------
__global__ __launch_bounds__(256) void proj_kvf(
    const float* __restrict__ X2,
    const bf16* __restrict__ Wk, const float* __restrict__ bk,
    const bf16* __restrict__ Wv, const float* __restrict__ bv,
    bf16* __restrict__ Kf, bf16* __restrict__ Vf, int M)
{
    __shared__ alignas(16) char sX[64 * 256];     // staged x2 tile (swizzled bf16)
    __shared__ alignas(16) char rbuf[64 * 256];   // repack buffer
    int tid = threadIdx.x;
    int lane = tid & 63, wave = tid >> 6;
    int l16 = lane & 15, lhi = lane >> 4;
    int l31 = lane & 31, lh5 = lane >> 5;
    long long r0 = (long long)blockIdx.x * 64;    // flattened (b*M + m0)
    int b = (int)(r0 / M);
    int m0 = (int)(r0 % M);
    {
        int row = tid >> 2, seg = tid & 3;
        const float4* src = reinterpret_cast<const float4*>(X2 + (r0 + row) * 128 + seg * 32);
        int swz = (row & 7) << 4;
        char* dst0 = &sX[0] + row * 256;
#pragma unroll
        for (int i = 0; i < 8; ++i) {
            float4 v = src[i];
            bf16* d = (bf16*)(dst0 + ((seg * 64 + i * 8) ^ swz));
            d[0] = __float2bfloat16(v.x); d[1] = __float2bfloat16(v.y);
            d[2] = __float2bfloat16(v.z); d[3] = __float2bfloat16(v.w);
        }
    }
    __syncthreads();

    // ---------------- K phase ----------------
    {
        int rloc = wave * 16 + l16;
        int swzr = (rloc & 7) << 4;
        short8 a[4];
#pragma unroll
        for (int c4 = 0; c4 < 4; ++c4)
            a[c4] = *(const short8*)(&sX[0] + ((rloc * 256 + lhi * 16 + c4 * 64) ^ swzr));
        f32x4 acc[8] = {};
#pragma unroll
        for (int n = 0; n < 8; ++n) {
            const bf16* wr = Wk + (n * 16 + l16) * 128 + lhi * 8;
#pragma unroll
            for (int c4 = 0; c4 < 4; ++c4)
                acc[n] = MFMA(a[c4], *(const short8*)(wr + c4 * 32), acc[n]);
        }
#pragma unroll
        for (int n = 0; n < 8; ++n) {
            float bia = bk[l16 + 16 * n];
#pragma unroll
            for (int r = 0; r < 4; ++r) {
                int row = wave * 16 + lhi * 4 + r;
                *(bf16*)(&rbuf[0] + ((row * 256 + (l16 + 16 * n) * 2) ^ ((row & 7) << 4))) =
                    __float2bfloat16(acc[n][r] + bia);
            }
        }
    }
    __syncthreads();
    // emit Kf: wave w -> tile t32 = w>>1, frags f = (w&1)*4 .. +3
    {
        int t32 = wave >> 1;
        int fb = (wave & 1) * 4;
#pragma unroll
        for (int fi = 0; fi < 4; ++fi) {
            int f = fb + fi;
            int row = t32 * 32 + l31;
            int colb = f * 32 + lh5 * 16;
            short8 v = *(const short8*)(&rbuf[0] + row * 256 + (colb ^ ((row & 7) << 4)));
            long long t32g = (r0 >> 5) + t32;
            *(short8*)(Kf + (t32g * 8 + f) * 512 + lane * 8) = v;
        }
    }

    // ---------------- V phase (sX still intact) ----------------
    int w0 = wave * 32;
    short8 a2[2][4];
#pragma unroll
    for (int wt = 0; wt < 2; ++wt) {
        const bf16* wr = Wv + (w0 + wt * 16 + l16) * 128 + lhi * 8;
#pragma unroll
        for (int c4 = 0; c4 < 4; ++c4) a2[wt][c4] = *(const short8*)(wr + c4 * 32);
    }
    f32x4 acc2[2][4] = {};
#pragma unroll
    for (int mtl = 0; mtl < 4; ++mtl) {
        int rloc = mtl * 16 + l16;
        int swzr = (rloc & 7) << 4;
#pragma unroll
        for (int c4 = 0; c4 < 4; ++c4) {
            short8 xb = *(const short8*)(&sX[0] + ((rloc * 256 + lhi * 16 + c4 * 64) ^ swzr));
            acc2[0][mtl] = MFMA(a2[0][c4], xb, acc2[0][mtl]);
            acc2[1][mtl] = MFMA(a2[1][c4], xb, acc2[1][mtl]);
        }
    }
    __syncthreads();   // all Kf emission reads of rbuf done
    // V -> rbuf as sV: [w=128][m=64] bf16 swizzled
#pragma unroll
    for (int wt = 0; wt < 2; ++wt) {
#pragma unroll
        for (int r = 0; r < 4; ++r) {
            int w = w0 + wt * 16 + lhi * 4 + r;
            float bia = bv[w];
#pragma unroll
            for (int mtl = 0; mtl < 4; ++mtl) {
                int mloc = mtl * 16 + l16;
                *(bf16*)(&rbuf[0] + ((w * 128 + mloc * 2) ^ ((w & 7) << 4))) =
                    __float2bfloat16(acc2[wt][mtl][r] + bia);
            }
        }
    }
    __syncthreads();
    // emit Vf: wave w -> t32 = w>>1, kvh = w&1, wc = 0..3
    {
        int t32 = wave >> 1, kvh = wave & 1;
#pragma unroll
        for (int wc = 0; wc < 4; ++wc) {
            int row = wc * 32 + l31;                    // w index
            int colb = t32 * 64 + kvh * 32 + lh5 * 16;  // m byte offset
            short8 v = *(const short8*)(&rbuf[0] + row * 128 + (colb ^ ((row & 7) << 4)));
            long long g32 = (long long)b * (M >> 5) + (m0 >> 5) + t32;
            *(short8*)(Vf + (g32 * 8 + kvh * 4 + wc) * 512 + lane * 8) = v;
        }
    }
}

// ---------------------------------------------------------------------------
// Flash attention on mfma_f32_32x32x16_bf16 (R16): each wave owns 32 q-rows;
// the same 8 K-frag + 8 V-frag LDS reads per 32-kv tile now feed 32 q-rows
// (2x amortization vs the 16x16 path). Swapped QK (D = S^T: col=q=lane&31,
// row=kv=(reg&3)+8*(reg>>2)+4*(lane>>5)) keeps softmax lane-local; P->A-frag
// needs only 2x 64-bit shfl_xor(32) hi-half block exchanges. Fixed-max
// softmax; K/V/mask double-buffered block-cooperative LDS staging (R10);
// KV-split=2. launch_bounds(256,2): acc 64 + aq 32 + staging ~ 155 VGPR.
// WRITE_SIZE tripwire: steady-state must stay ~30 MB (else spilling).
// ---------------------------------------------------------------------------
__global__ __launch_bounds__(256, 2) void attn_split(
    const bf16* __restrict__ Q, const bf16* __restrict__ Kf, const bf16* __restrict__ Vf,
    const void* __restrict__ maskp, const int* __restrict__ flagp,
    __half* __restrict__ pacc, float* __restrict__ pml,
    int B, int N, int M)
{
    __shared__ alignas(16) char kbuf[2][8192];           // 8 frags x 1KB (32kv x 128ch)
    __shared__ alignas(16) char vbuf[2][8192];           // 8 frags x 1KB
    __shared__ alignas(16) unsigned char smask[4][1024]; // per-wave 32q x 32kv bytes
    int nq = N >> 7;                                      // 128 q-rows per block
    int nwg = gridDim.x;
    int bid = blockIdx.x;
    int wg = ((nwg & 7) == 0) ? ((bid & 7) * (nwg >> 3) + (bid >> 3)) : bid;
    int qt = wg % nq;
    int s  = (wg / nq) % SPLIT;
    int b  = wg / (nq * SPLIT);
    int tid = threadIdx.x;
    int lane = tid & 63, wave = tid >> 6;
    int l31 = lane & 31, hi = lane >> 5;
    int q0w = qt * 128 + wave * 32;
    int Mh = M / SPLIT;
    int mbase = s * Mh;
    long long R = (long long)B * N;
    int fl4 = (*flagp == 0);
    const int NT = Mh >> 5;   // 32-kv tiles

    // Q fragments (B operand): Q[q0w + l31][f*16 + hi*8 .. +7]
    const bf16* qbase = Q + ((long long)b * N + q0w + l31) * 128 + hi * 8;
    short8 aq[8];
#pragma unroll
    for (int f = 0; f < 8; ++f) aq[f] = *(const short8*)(qbase + f * 16);

    long long kt32 = ((long long)b * M + mbase) >> 5;   // 32-kv tile index base

    // mask staging: lane covers q-row (lane>>1), 16 bytes at (lane&1)*16
    int srow = lane >> 1, scol = (lane & 1) * 16;
    long long mrowE = ((long long)b * N + q0w + srow) * (long long)M + mbase + scol;

    unsigned char* smw = &smask[wave][0];

    f32x16 acc[4] = {};   // per w-chunk (wc*32 + l31)
    float plsum = 0.f;    // partial row sum for q = l31 (this lane's 16 kv/tile)

    auto mloadB = [&](int t) -> int4 {
        return *(const int4*)((const unsigned char*)maskp + mrowE + (long long)t * 32);
    };
    auto mload4 = [&](int t) -> int4 {
        const int* mp = (const int*)maskp;
        int4 r;
        unsigned int wd[4];
#pragma unroll
        for (int c = 0; c < 4; ++c) {
            int4 x = *(const int4*)(mp + mrowE + (long long)t * 32 + c * 4);
            wd[c] = (x.x ? 1u : 0u) | ((x.y ? 1u : 0u) << 8) |
                    ((x.z ? 1u : 0u) << 16) | ((x.w ? 1u : 0u) << 24);
        }
        r.x = (int)wd[0]; r.y = (int)wd[1]; r.z = (int)wd[2]; r.w = (int)wd[3];
        return r;
    };

    // ---- prologue: stage K/V tile 0 + mask tile 0 ----
    {
        int4 k0 = *(const int4*)(Kf + (kt32 * 8 + wave * 2 + 0) * 512 + lane * 8);
        int4 k1 = *(const int4*)(Kf + (kt32 * 8 + wave * 2 + 1) * 512 + lane * 8);
        int4 v0 = *(const int4*)(Vf + (kt32 * 8 + wave * 2 + 0) * 512 + lane * 8);
        int4 v1 = *(const int4*)(Vf + (kt32 * 8 + wave * 2 + 1) * 512 + lane * 8);
        int4 mreg = fl4 ? mload4(0) : mloadB(0);
        *(int4*)(&kbuf[0][(wave * 2 + 0) * 1024 + lane * 16]) = k0;
        *(int4*)(&kbuf[0][(wave * 2 + 1) * 1024 + lane * 16]) = k1;
        *(int4*)(&vbuf[0][(wave * 2 + 0) * 1024 + lane * 16]) = v0;
        *(int4*)(&vbuf[0][(wave * 2 + 1) * 1024 + lane * 16]) = v1;
        *(int4*)(smw + srow * 32 + scol) = mreg;
        __syncthreads();
    }

    for (int t = 0; t < NT; ++t) {
        int cur = t & 1;
        // ---- 1. issue staging loads for tile t+1 ----
        int4 ks0, ks1, vs0, vs1, mreg;
        bool nxt = (t + 1 < NT);
        if (nxt) {
            long long F = (kt32 + t + 1) * 8 + wave * 2;
            ks0 = *(const int4*)(Kf + F * 512 + lane * 8);
            ks1 = *(const int4*)(Kf + (F + 1) * 512 + lane * 8);
            vs0 = *(const int4*)(Vf + F * 512 + lane * 8);
            vs1 = *(const int4*)(Vf + (F + 1) * 512 + lane * 8);
            mreg = fl4 ? mload4(t + 1) : mloadB(t + 1);
        }

        // ---- 2. S^T = K Q^T (8 x 32x32x16 MFMA) ----
        __builtin_amdgcn_s_setprio(1);
        f32x16 sv = {};
#pragma unroll
        for (int f = 0; f < 8; ++f)
            sv = MFMA32(*(const short8*)(&kbuf[cur][f * 1024 + lane * 16]), aq[f], sv);
        __builtin_amdgcn_s_setprio(0);

        // ---- 3. lane-local softmax (q = l31; kv = 8G + 4hi + r) ----
        uint2 Bb[4];
#pragma unroll
        for (int G = 0; G < 4; ++G) {
            unsigned int mk = *(const unsigned int*)(smw + l31 * 32 + G * 8 + hi * 4);
            float p0 = (mk & 0x000000ffu) ? 0.f : exp2f(sv[G * 4 + 0]);
            float p1 = (mk & 0x0000ff00u) ? 0.f : exp2f(sv[G * 4 + 1]);
            float p2 = (mk & 0x00ff0000u) ? 0.f : exp2f(sv[G * 4 + 2]);
            float p3 = (mk & 0xff000000u) ? 0.f : exp2f(sv[G * 4 + 3]);
            plsum += (p0 + p1) + (p2 + p3);
            unsigned int w0, w1;
            asm("v_cvt_pk_bf16_f32 %0, %1, %2" : "=v"(w0) : "v"(p0), "v"(p1));
            asm("v_cvt_pk_bf16_f32 %0, %1, %2" : "=v"(w1) : "v"(p2), "v"(p3));
            Bb[G].x = w0; Bb[G].y = w1;
        }

        // ---- 4. P -> A-frags via two 64-bit hi-half exchanges (xor 32) ----
        uint2 sA = hi ? Bb[0] : Bb[1];
        uint2 rA;
        rA.x = __shfl_xor((int)sA.x, 32);
        rA.y = __shfl_xor((int)sA.y, 32);
        uint2 sB = hi ? Bb[2] : Bb[3];
        uint2 rB;
        rB.x = __shfl_xor((int)sB.x, 32);
        rB.y = __shfl_xor((int)sB.y, 32);
        unsigned int paw0[4], paw1[4];
        if (hi == 0) {
            paw0[0] = Bb[0].x; paw0[1] = Bb[0].y; paw0[2] = rA.x; paw0[3] = rA.y;
            paw1[0] = Bb[2].x; paw1[1] = Bb[2].y; paw1[2] = rB.x; paw1[3] = rB.y;
        } else {
            paw0[0] = rA.x; paw0[1] = rA.y; paw0[2] = Bb[1].x; paw0[3] = Bb[1].y;
            paw1[0] = rB.x; paw1[1] = rB.y; paw1[2] = Bb[3].x; paw1[3] = Bb[3].y;
        }
        short8 pa0 = *(const short8*)paw0;
        short8 pa1 = *(const short8*)paw1;

        // ---- 5. O += P V (8 x 32x32x16 MFMA, 4 independent chains) ----
        __builtin_amdgcn_s_setprio(1);
#pragma unroll
        for (int wc = 0; wc < 4; ++wc) {
            acc[wc] = MFMA32(pa0, *(const short8*)(&vbuf[cur][(0 * 4 + wc) * 1024 + lane * 16]), acc[wc]);
            acc[wc] = MFMA32(pa1, *(const short8*)(&vbuf[cur][(1 * 4 + wc) * 1024 + lane * 16]), acc[wc]);
        }
        __builtin_amdgcn_s_setprio(0);

        // ---- 6. land staged tile t+1; barrier ----
        if (nxt) {
            int nx = cur ^ 1;
            *(int4*)(&kbuf[nx][(wave * 2 + 0) * 1024 + lane * 16]) = ks0;
            *(int4*)(&kbuf[nx][(wave * 2 + 1) * 1024 + lane * 16]) = ks1;
            *(int4*)(&vbuf[nx][(wave * 2 + 0) * 1024 + lane * 16]) = vs0;
            *(int4*)(&vbuf[nx][(wave * 2 + 1) * 1024 + lane * 16]) = vs1;
            *(int4*)(smw + srow * 32 + scol) = mreg;
            __syncthreads();
        }
    }

    // ---- epilogue: full row sum = this lane + partner (kv halves) ----
    float lsum = plsum + __shfl_xor(plsum, 32);
    float invq = (lsum > 0.f) ? 1.f / lsum : 0.f;
    float iv[16];
#pragma unroll
    for (int reg = 0; reg < 16; ++reg) {
        int qr = (reg & 3) + 8 * (reg >> 2) + 4 * hi;
        iv[reg] = __shfl(invq, qr);
    }
    long long brow = (long long)b * N + q0w;
#pragma unroll
    for (int wc = 0; wc < 4; ++wc)
#pragma unroll
        for (int reg = 0; reg < 16; ++reg) {
            int qr = (reg & 3) + 8 * (reg >> 2) + 4 * hi;
            pacc[((long long)s * R + brow + qr) * 128 + wc * 32 + l31] =
                __float2half(acc[wc][reg] * iv[reg]);
        }
    if (lane < 32)
        pml[(long long)s * R + brow + lane] = lsum;
}

// ---------------------------------------------------------------------------
// Combine SPLIT normalized f16 partials (weights l_s), LayerNorm, residual.
// One wave per row.
// ---------------------------------------------------------------------------
__global__ __launch_bounds__(256) void combine(
    const __half* __restrict__ pacc, const float* __restrict__ pml,
    const float* __restrict__ lng, const float* __restrict__ lnb,
    const float* __restrict__ x1, float* __restrict__ out, long long R)
{
    int tid = threadIdx.x;
    int lane = tid & 63, wave = tid >> 6;
    long long row = (long long)blockIdx.x * 4 + wave;
    float l[SPLIT];
    float den = 0.f;
#pragma unroll
    for (int s = 0; s < SPLIT; ++s) {
        l[s] = pml[(long long)s * R + row];
        den += l[s];
    }
    float inv = (den > 0.f) ? 1.f / den : 0.f;
    int c0 = lane * 2;
    float xa = 0.f, xb = 0.f;
#pragma unroll
    for (int s = 0; s < SPLIT; ++s) {
        const __half* hp = pacc + ((long long)s * R + row) * 128 + c0;
        xa += l[s] * __half2float(hp[0]);
        xb += l[s] * __half2float(hp[1]);
    }
    xa *= inv; xb *= inv;
    float su = xa + xb;
#pragma unroll
    for (int o = 1; o < 64; o <<= 1) su += __shfl_xor(su, o);
    float mu = su * (1.f / 128.f);
    float da = xa - mu, db = xb - mu;
    float sq = da * da + db * db;
#pragma unroll
    for (int o = 1; o < 64; o <<= 1) sq += __shfl_xor(sq, o);
    float rstd = rsqrtf(sq * (1.f / 128.f) + 1e-5f);
    float2 xr = *(const float2*)(x1 + row * 128 + c0);
    float2 o2;
    o2.x = da * rstd * lng[c0] + lnb[c0] + xr.x;
    o2.y = db * rstd * lng[c0 + 1] + lnb[c0 + 1] + xr.y;
    *(float2*)(out + row * 128 + c0) = o2;
}

// ---------------------------------------------------------------------------
extern "C" void kernel_launch(void* const* d_in, const int* in_sizes, int n_in,
                              void* d_out, int out_size, void* d_ws, size_t ws_size,
                              hipStream_t stream)
{
    const float* x1 = (const float*)d_in[0];
    const float* x2 = (const float*)d_in[1];
    const void* mask = d_in[2];
    const float* qw = (const float*)d_in[3];
    const float* qb = (const float*)d_in[4];
    const float* kw = (const float*)d_in[5];
    const float* kb = (const float*)d_in[6];
    const float* vw = (const float*)d_in[7];
    const float* vb = (const float*)d_in[8];
    const float* lng = (const float*)d_in[9];
    const float* lnb = (const float*)d_in[10];

    long long a = (long long)in_sizes[0] / 128;   // B*N
    long long c = (long long)in_sizes[1] / 128;   // B*M
    long long mm = (long long)in_sizes[2];        // B*N*M
    int B = (int)((a * c) / mm);
    int N = (int)(a / B);
    int M = (int)(c / B);
    long long R = a;

    char* p = (char*)d_ws;
    bf16* Q = (bf16*)p;    p += (size_t)a * 128 * sizeof(bf16);
    bf16* Kf = (bf16*)p;   p += (size_t)c * 128 * sizeof(bf16);
    bf16* Vf = (bf16*)p;   p += (size_t)c * 128 * sizeof(bf16);
    float* T = (float*)p;  p += 3 * 128 * 128 * sizeof(float);
    float* bt = (float*)p; p += 3 * 128 * sizeof(float);
    float* beff = (float*)p; p += 3 * 128 * sizeof(float);
    bf16* Weff = (bf16*)p; p += 3 * 128 * 128 * sizeof(bf16);
    int* flag = (int*)p;   p += 256;
    __half* pacc = (__half*)p; p += (size_t)SPLIT * R * 128 * sizeof(__half);
    float* pml = (float*)p;    p += (size_t)SPLIT * R * sizeof(float);

    detect_mask<<<1, 256, 0, stream>>>((const unsigned int*)mask, flag);
    compose_a<<<384, 128, 0, stream>>>(qw, qb, kw, kb, vw, vb, T, bt);
    compose_b<<<384, 128, 0, stream>>>(qw, qb, kw, kb, vw, vb, T, bt, Weff, beff);

    proj_rm<<<(int)(a / 64), 256, 0, stream>>>(x1, Weff, beff, Q);
    proj_kvf<<<(int)(c / 64), 256, 0, stream>>>(x2, Weff + 16384, beff + 128,
                                                Weff + 2 * 16384, beff + 256, Kf, Vf, M);

    int nblk = B * (N / 128) * SPLIT;
    attn_split<<<nblk, 256, 0, stream>>>(Q, Kf, Vf, mask, flag, pacc, pml, B, N, M);
    combine<<<(int)(R / 4), 256, 0, stream>>>(pacc, pml, lng, lnb, x1, (float*)d_out, R);
}

// Round 17
// 157.683 us; speedup vs baseline: 1.0161x; 1.0161x over previous
//
#include <hip/hip_runtime.h>
#include <hip/hip_bf16.h>
#include <hip/hip_fp16.h>

typedef __hip_bfloat16 bf16;
typedef __attribute__((ext_vector_type(8))) short short8;
typedef __attribute__((ext_vector_type(4))) float f32x4;

#define MFMA(a, b, c) __builtin_amdgcn_mfma_f32_16x16x32_bf16((a), (b), (c), 0, 0, 0)
#define SPLIT 2

// ---------------------------------------------------------------------------
// compose_a + mask detection fused. Blocks 0..383: T = W2*W1, bt = W2*b1+b2.
// Block 384: mask element-size detection (flag=0 -> 4B elems, 1 -> bytes).
// ---------------------------------------------------------------------------
__global__ void compose_a(const float* __restrict__ qw, const float* __restrict__ qb,
                          const float* __restrict__ kw, const float* __restrict__ kb,
                          const float* __restrict__ vw, const float* __restrict__ vb,
                          const unsigned int* __restrict__ mask,
                          float* __restrict__ T, float* __restrict__ bt,
                          int* __restrict__ flag)
{
    if (blockIdx.x == 384) {
        __shared__ int bad;
        if (threadIdx.x == 0) bad = 0;
        __syncthreads();
        if (threadIdx.x < 256) {
            unsigned int w = mask[threadIdx.x];
            bool ok = (w == 0u) || (w == 1u) || (w == 0x3F800000u);
            if (!ok) atomicAdd(&bad, 1);
        }
        __syncthreads();
        if (threadIdx.x == 0) *flag = (bad == 0) ? 0 : 1;
        return;
    }
    int h = blockIdx.x >> 7;
    int i = blockIdx.x & 127;
    int j = threadIdx.x;
    const float* W = (h == 0) ? qw : (h == 1) ? kw : vw;
    const float* bv = (h == 0) ? qb : (h == 1) ? kb : vb;
    const float* W1 = W;
    const float* W2 = W + 128 * 128;
    float acc = 0.f;
    for (int k = 0; k < 128; ++k) acc += W2[i * 128 + k] * W1[k * 128 + j];
    T[h * 16384 + i * 128 + j] = acc;
    if (j == 0) {
        float bacc = 0.f;
        for (int k = 0; k < 128; ++k) bacc += W2[i * 128 + k] * bv[k];
        bt[h * 128 + i] = bacc + bv[128 + i];
    }
}

__global__ void compose_b(const float* __restrict__ qw, const float* __restrict__ qb,
                          const float* __restrict__ kw, const float* __restrict__ kb,
                          const float* __restrict__ vw, const float* __restrict__ vb,
                          const float* __restrict__ T, const float* __restrict__ bt,
                          bf16* __restrict__ Weff, float* __restrict__ beff)
{
    int h = blockIdx.x >> 7;
    int i = blockIdx.x & 127;
    int j = threadIdx.x;
    const float* W = (h == 0) ? qw : (h == 1) ? kw : vw;
    const float* bv = (h == 0) ? qb : (h == 1) ? kb : vb;
    const float* W3 = W + 2 * 128 * 128;
    const float* Th = T + h * 16384;
    float acc = 0.f;
    for (int k = 0; k < 128; ++k) acc += W3[i * 128 + k] * Th[k * 128 + j];
    float scale = (h == 0) ? (1.4426950408889634f * rsqrtf(128.0f)) : 1.0f;
    Weff[h * 16384 + i * 128 + j] = __float2bfloat16(acc * scale);
    if (j == 0) {
        float bacc = 0.f;
        for (int k = 0; k < 128; ++k) bacc += W3[i * 128 + k] * bt[h * 128 + k];
        beff[h * 128 + i] = (bacc + bv[256 + i]) * scale;
    }
}

// ---------------------------------------------------------------------------
// Q projection, row-major output: Y[r][w] = sum_c X[r][c]*W[w][c] + bias[w]
// ---------------------------------------------------------------------------
__global__ __launch_bounds__(256) void proj_rm(
    const float* __restrict__ X, const bf16* __restrict__ Wb,
    const float* __restrict__ bias, bf16* __restrict__ Y)
{
    __shared__ alignas(16) char sX[64 * 256];
    int tid = threadIdx.x;
    int lane = tid & 63, wave = tid >> 6;
    int l16 = lane & 15, lhi = lane >> 4;
    long long r0 = (long long)blockIdx.x * 64;
    {
        int row = tid >> 2, seg = tid & 3;
        const float4* src = reinterpret_cast<const float4*>(X + (r0 + row) * 128 + seg * 32);
        int swz = (row & 7) << 4;
        char* dst0 = &sX[0] + row * 256;
#pragma unroll
        for (int i = 0; i < 8; ++i) {
            float4 v = src[i];
            bf16* d = (bf16*)(dst0 + ((seg * 64 + i * 8) ^ swz));
            d[0] = __float2bfloat16(v.x); d[1] = __float2bfloat16(v.y);
            d[2] = __float2bfloat16(v.z); d[3] = __float2bfloat16(v.w);
        }
    }
    __syncthreads();
    int rloc = wave * 16 + l16;
    int swzr = (rloc & 7) << 4;
    short8 a[4];
#pragma unroll
    for (int c4 = 0; c4 < 4; ++c4)
        a[c4] = *(const short8*)(&sX[0] + ((rloc * 256 + lhi * 16 + c4 * 64) ^ swzr));
    f32x4 acc[8] = {};
#pragma unroll
    for (int n = 0; n < 8; ++n) {
        const bf16* wr = Wb + (n * 16 + l16) * 128 + lhi * 8;
#pragma unroll
        for (int c4 = 0; c4 < 4; ++c4)
            acc[n] = MFMA(a[c4], *(const short8*)(wr + c4 * 32), acc[n]);
    }
#pragma unroll
    for (int n = 0; n < 8; ++n) {
        float bia = bias[l16 + 16 * n];
#pragma unroll
        for (int r = 0; r < 4; ++r) {
            long long q = r0 + wave * 16 + lhi * 4 + r;
            Y[q * 128 + l16 + 16 * n] = __float2bfloat16(acc[n][r] + bia);
        }
    }
}

// ---------------------------------------------------------------------------
// FUSED K+V projection: one x2 LDS stage serves both heads. K emitted in
// QK^T B-fragment order, V in PV B-fragment order (coalesced 1KB bursts).
// ---------------------------------------------------------------------------
__global__ __launch_bounds__(256) void proj_kvf(
    const float* __restrict__ X2,
    const bf16* __restrict__ Wk, const float* __restrict__ bk,
    const bf16* __restrict__ Wv, const float* __restrict__ bv,
    bf16* __restrict__ Kf, bf16* __restrict__ Vf, int M)
{
    __shared__ alignas(16) char sX[64 * 256];     // staged x2 tile (swizzled bf16)
    __shared__ alignas(16) char rbuf[64 * 256];   // repack buffer
    int tid = threadIdx.x;
    int lane = tid & 63, wave = tid >> 6;
    int l16 = lane & 15, lhi = lane >> 4;
    long long r0 = (long long)blockIdx.x * 64;    // flattened (b*M + m0)
    int b = (int)(r0 / M);
    int m0 = (int)(r0 % M);
    {
        int row = tid >> 2, seg = tid & 3;
        const float4* src = reinterpret_cast<const float4*>(X2 + (r0 + row) * 128 + seg * 32);
        int swz = (row & 7) << 4;
        char* dst0 = &sX[0] + row * 256;
#pragma unroll
        for (int i = 0; i < 8; ++i) {
            float4 v = src[i];
            bf16* d = (bf16*)(dst0 + ((seg * 64 + i * 8) ^ swz));
            d[0] = __float2bfloat16(v.x); d[1] = __float2bfloat16(v.y);
            d[2] = __float2bfloat16(v.z); d[3] = __float2bfloat16(v.w);
        }
    }
    __syncthreads();

    // ---------------- K phase ----------------
    {
        int rloc = wave * 16 + l16;
        int swzr = (rloc & 7) << 4;
        short8 a[4];
#pragma unroll
        for (int c4 = 0; c4 < 4; ++c4)
            a[c4] = *(const short8*)(&sX[0] + ((rloc * 256 + lhi * 16 + c4 * 64) ^ swzr));
        f32x4 acc[8] = {};
#pragma unroll
        for (int n = 0; n < 8; ++n) {
            const bf16* wr = Wk + (n * 16 + l16) * 128 + lhi * 8;
#pragma unroll
            for (int c4 = 0; c4 < 4; ++c4)
                acc[n] = MFMA(a[c4], *(const short8*)(wr + c4 * 32), acc[n]);
        }
#pragma unroll
        for (int n = 0; n < 8; ++n) {
            float bia = bk[l16 + 16 * n];
#pragma unroll
            for (int r = 0; r < 4; ++r) {
                int row = wave * 16 + lhi * 4 + r;
                *(bf16*)(&rbuf[0] + ((row * 256 + (l16 + 16 * n) * 2) ^ ((row & 7) << 4))) =
                    __float2bfloat16(acc[n][r] + bia);
            }
        }
    }
    __syncthreads();
#pragma unroll
    for (int c4 = 0; c4 < 4; ++c4) {
        int row = wave * 16 + l16;
        short8 v = *(const short8*)(&rbuf[0] +
            ((row * 256 + c4 * 64 + lhi * 16) ^ ((row & 7) << 4)));
        long long tile = (r0 >> 4) + wave;
        *(short8*)(Kf + (tile * 4 + c4) * 512 + lane * 8) = v;
    }

    // ---------------- V phase (sX still intact) ----------------
    int w0 = wave * 32;
    short8 a2[2][4];
#pragma unroll
    for (int wt = 0; wt < 2; ++wt) {
        const bf16* wr = Wv + (w0 + wt * 16 + l16) * 128 + lhi * 8;
#pragma unroll
        for (int c4 = 0; c4 < 4; ++c4) a2[wt][c4] = *(const short8*)(wr + c4 * 32);
    }
    f32x4 acc2[2][4] = {};
#pragma unroll
    for (int mtl = 0; mtl < 4; ++mtl) {
        int rloc = mtl * 16 + l16;
        int swzr = (rloc & 7) << 4;
#pragma unroll
        for (int c4 = 0; c4 < 4; ++c4) {
            short8 xb = *(const short8*)(&sX[0] + ((rloc * 256 + lhi * 16 + c4 * 64) ^ swzr));
            acc2[0][mtl] = MFMA(a2[0][c4], xb, acc2[0][mtl]);
            acc2[1][mtl] = MFMA(a2[1][c4], xb, acc2[1][mtl]);
        }
    }
    __syncthreads();   // all Kf emission reads of rbuf done
#pragma unroll
    for (int wt = 0; wt < 2; ++wt) {
#pragma unroll
        for (int r = 0; r < 4; ++r) {
            int w = w0 + wt * 16 + lhi * 4 + r;
            float bia = bv[w];
#pragma unroll
            for (int mtl = 0; mtl < 4; ++mtl) {
                int mloc = mtl * 16 + l16;
                *(bf16*)(&rbuf[0] + ((w * 128 + mloc * 2) ^ ((w & 7) << 4))) =
                    __float2bfloat16(acc2[wt][mtl][r] + bia);
            }
        }
    }
    __syncthreads();
#pragma unroll
    for (int q = 0; q < 4; ++q) {
        int fr = wave * 4 + q;
        int gloc = fr >> 3, n = fr & 7;
        int row = n * 16 + l16;
        short8 v = *(const short8*)(&rbuf[0] +
            ((row * 128 + gloc * 64 + lhi * 16) ^ ((row & 7) << 4)));
        long long g = (long long)b * (M >> 5) + (m0 >> 5) + gloc;
        *(short8*)(Vf + (g * 8 + n) * 512 + lane * 8) = v;
    }
}

// ---------------------------------------------------------------------------
// Flash attention (R13 best): KV-split=2, fixed-max softmax, swapped QK^T,
// K/V/mask block-cooperative double-buffered LDS staging, ZERO-LDS P
// redistribution via two 64-bit shfl_xor exchanges. setprio around MFMAs.
// NOTE (R4/R8): never raise waves/EU via launch_bounds (spill explosion).
// NOTE (R12): block-shared operands (K, V) stay in LDS.
// NOTE (R14/R16): bigger tiles / 32x32 MFMA are neutral-to-worse; the loop
// is latency-plateaued at 16 waves/CU, not LDS-op-count-bound.
// ---------------------------------------------------------------------------
__global__ __launch_bounds__(256, 4) void attn_split(
    const bf16* __restrict__ Q, const bf16* __restrict__ Kf, const bf16* __restrict__ Vf,
    const void* __restrict__ maskp, const int* __restrict__ flagp,
    __half* __restrict__ pacc, float* __restrict__ pml,
    int B, int N, int M)
{
    __shared__ alignas(16) char kbuf[2][8192];          // 32kv x 128ch bf16, frag order
    __shared__ alignas(16) char vbuf[2][8192];          // 8 frags x 1KB
    __shared__ alignas(16) unsigned char smask[4][512]; // per-wave 16q x 32kv mask bytes
    int nq = N >> 6;
    int nwg = gridDim.x;
    int bid = blockIdx.x;
    int wg = ((nwg & 7) == 0) ? ((bid & 7) * (nwg >> 3) + (bid >> 3)) : bid;
    int qt = wg % nq;
    int s  = (wg / nq) % SPLIT;
    int b  = wg / (nq * SPLIT);
    int tid = threadIdx.x;
    int lane = tid & 63, wave = tid >> 6;
    int l16 = lane & 15, lhi = lane >> 4;
    int q0 = qt * 64 + wave * 16;
    int Mh = M / SPLIT;
    int mbase = s * Mh;
    long long R = (long long)B * N;
    int fl4 = (*flagp == 0);
    const int NT = Mh >> 5;   // 32-kv tiles

    const bf16* qptr = Q + ((long long)b * N + q0 + l16) * 128 + lhi * 8;
    short8 aq[4];
#pragma unroll
    for (int c4 = 0; c4 < 4; ++c4) aq[c4] = *(const short8*)(qptr + c4 * 32);

    long long ktile0 = ((long long)b * M + mbase) >> 4;   // 16-wide kv tiles
    long long gbase  = ((long long)b * M + mbase) >> 5;   // 32-wide kv groups

    int srow = lane >> 2, soff = (lane & 3) * 8;
    long long mrowb = ((long long)b * N + q0 + srow) * (long long)M + mbase + soff;

    unsigned char* smw = &smask[wave][0];

    f32x4 acc[8] = {};
    float plsum = 0.f;   // per-lane partial sum for q-row l16

    auto mload = [&](int t) -> uint2 {
        uint2 r;
        if (fl4) {
            const int* mp = (const int*)maskp;
            const int4* pp = (const int4*)(mp + mrowb + (long long)t * 32);
            int4 a = pp[0], bb = pp[1];
            r.x = (a.x ? 1u : 0u) | ((a.y ? 1u : 0u) << 8) |
                  ((a.z ? 1u : 0u) << 16) | ((a.w ? 1u : 0u) << 24);
            r.y = (bb.x ? 1u : 0u) | ((bb.y ? 1u : 0u) << 8) |
                  ((bb.z ? 1u : 0u) << 16) | ((bb.w ? 1u : 0u) << 24);
        } else {
            r = *(const uint2*)((const unsigned char*)maskp + mrowb + (long long)t * 32);
        }
        return r;
    };

    // ---- prologue: stage K/V tile 0 + mask tile 0 ----
    {
        long long F = ktile0 * 4 + wave * 2;
        long long G = gbase * 8 + wave * 2;
        int4 k0 = *(const int4*)(Kf + F * 512 + lane * 8);
        int4 k1 = *(const int4*)(Kf + (F + 1) * 512 + lane * 8);
        int4 v0 = *(const int4*)(Vf + G * 512 + lane * 8);
        int4 v1 = *(const int4*)(Vf + (G + 1) * 512 + lane * 8);
        uint2 mreg = mload(0);
        *(int4*)(&kbuf[0][(wave * 2 + 0) * 1024 + lane * 16]) = k0;
        *(int4*)(&kbuf[0][(wave * 2 + 1) * 1024 + lane * 16]) = k1;
        *(int4*)(&vbuf[0][(wave * 2 + 0) * 1024 + lane * 16]) = v0;
        *(int4*)(&vbuf[0][(wave * 2 + 1) * 1024 + lane * 16]) = v1;
        *(uint2*)(smw + srow * 32 + soff) = mreg;
        __syncthreads();
    }

    for (int t = 0; t < NT; ++t) {
        int cur = t & 1;
        // ---- 1. issue staging loads for tile t+1 (hide under this iter) ----
        int4 ks0, ks1, vs0, vs1;
        uint2 mreg;
        bool nxt = (t + 1 < NT);
        if (nxt) {
            long long F = (ktile0 + 2LL * (t + 1)) * 4 + wave * 2;
            long long G = (gbase + (t + 1)) * 8 + wave * 2;
            ks0 = *(const int4*)(Kf + F * 512 + lane * 8);
            ks1 = *(const int4*)(Kf + (F + 1) * 512 + lane * 8);
            vs0 = *(const int4*)(Vf + G * 512 + lane * 8);
            vs1 = *(const int4*)(Vf + (G + 1) * 512 + lane * 8);
            mreg = mload(t + 1);
        }

        // ---- 2. S^T = K Q^T from LDS (swapped operands, 8 MFMAs) ----
        __builtin_amdgcn_s_setprio(1);
        f32x4 sv[2];
#pragma unroll
        for (int j = 0; j < 2; ++j) {
            f32x4 tt = {0.f, 0.f, 0.f, 0.f};
#pragma unroll
            for (int c4 = 0; c4 < 4; ++c4)
                tt = MFMA(*(const short8*)(&kbuf[cur][(j * 4 + c4) * 1024 + lane * 16]),
                          aq[c4], tt);
            sv[j] = tt;
        }
        __builtin_amdgcn_s_setprio(0);

        // ---- 3. lane-local softmax; pack kv-blocks B0 (a=g), B1 (a=g+4) ----
        uint2 Bb[2];
#pragma unroll
        for (int j = 0; j < 2; ++j) {
            unsigned int mk = *(const unsigned int*)(smw + l16 * 32 + 16 * j + lhi * 4);
            float p0 = (mk & 0x000000ffu) ? 0.f : exp2f(sv[j][0]);
            float p1 = (mk & 0x0000ff00u) ? 0.f : exp2f(sv[j][1]);
            float p2 = (mk & 0x00ff0000u) ? 0.f : exp2f(sv[j][2]);
            float p3 = (mk & 0xff000000u) ? 0.f : exp2f(sv[j][3]);
            plsum += (p0 + p1) + (p2 + p3);
            unsigned int w0, w1;
            asm("v_cvt_pk_bf16_f32 %0, %1, %2" : "=v"(w0) : "v"(p0), "v"(p1));
            asm("v_cvt_pk_bf16_f32 %0, %1, %2" : "=v"(w1) : "v"(p2), "v"(p3));
            Bb[j].x = w0; Bb[j].y = w1;
        }

        // ---- 4. in-register P redistribution (4x2 -> 2x4 block transpose) --
        uint2 X1 = (lhi < 2) ? Bb[1] : Bb[0];
        uint2 Qb;
        Qb.x = __shfl_xor((int)X1.x, 32);
        Qb.y = __shfl_xor((int)X1.y, 32);
        uint2 Pb = (lhi < 2) ? Bb[0] : Bb[1];
        uint2 X2 = (lhi == 1 || lhi == 2) ? Pb : Qb;
        uint2 Y2;
        Y2.x = __shfl_xor((int)X2.x, 16);
        Y2.y = __shfl_xor((int)X2.y, 16);
        uint2 s0 = (lhi == 0) ? Pb : (lhi == 1) ? Y2 : (lhi == 2) ? Qb : Y2;
        uint2 s1 = (lhi == 0) ? Y2 : (lhi == 1) ? Qb : (lhi == 2) ? Y2 : Pb;
        unsigned int paw[4] = {s0.x, s0.y, s1.x, s1.y};
        short8 pa = *(const short8*)paw;

        // ---- 5. O += P V from LDS (8 MFMAs) ----
        __builtin_amdgcn_s_setprio(1);
#pragma unroll
        for (int n = 0; n < 8; ++n)
            acc[n] = MFMA(pa, *(const short8*)(&vbuf[cur][n * 1024 + lane * 16]), acc[n]);
        __builtin_amdgcn_s_setprio(0);

        // ---- 6. land staged tile t+1 into the other buffer; barrier ----
        if (nxt) {
            int nx = cur ^ 1;
            *(int4*)(&kbuf[nx][(wave * 2 + 0) * 1024 + lane * 16]) = ks0;
            *(int4*)(&kbuf[nx][(wave * 2 + 1) * 1024 + lane * 16]) = ks1;
            *(int4*)(&vbuf[nx][(wave * 2 + 0) * 1024 + lane * 16]) = vs0;
            *(int4*)(&vbuf[nx][(wave * 2 + 1) * 1024 + lane * 16]) = vs1;
            *(uint2*)(smw + srow * 32 + soff) = mreg;
            __syncthreads();
        }
    }

    // ---- epilogue: full row-sum across the 4 lhi lanes of q-row l16 ----
    float lsum = plsum;
    lsum += __shfl_xor(lsum, 16);
    lsum += __shfl_xor(lsum, 32);
    float invq = (lsum > 0.f) ? 1.f / lsum : 0.f;
    float inv[4];
#pragma unroll
    for (int r = 0; r < 4; ++r) inv[r] = __shfl(invq, lhi * 4 + r);
    long long rowg[4];
#pragma unroll
    for (int r = 0; r < 4; ++r) rowg[r] = (long long)b * N + q0 + lhi * 4 + r;
#pragma unroll
    for (int n = 0; n < 8; ++n)
#pragma unroll
        for (int r = 0; r < 4; ++r)
            pacc[((long long)s * R + rowg[r]) * 128 + l16 + 16 * n] =
                __float2half(acc[n][r] * inv[r]);
    if (lhi == 0)
        pml[(long long)s * R + (long long)b * N + q0 + l16] = lsum;
}

// ---------------------------------------------------------------------------
// Combine (R17 vectorized): 2 rows per wave, 32 lanes/row x 4 channels.
// All global accesses are 16B (float4) or 8B (4x f16). Reductions span the
// 32-lane half only (xor 1..16). LayerNorm + residual fused.
// ---------------------------------------------------------------------------
__global__ __launch_bounds__(256) void combine(
    const __half* __restrict__ pacc, const float* __restrict__ pml,
    const float* __restrict__ lng, const float* __restrict__ lnb,
    const float* __restrict__ x1, float* __restrict__ out, long long R)
{
    int tid = threadIdx.x;
    int lane = tid & 63, wave = tid >> 6;
    int hi = lane >> 5, l31 = lane & 31;
    long long row = (long long)blockIdx.x * 8 + wave * 2 + hi;
    float l[SPLIT];
    float den = 0.f;
#pragma unroll
    for (int s = 0; s < SPLIT; ++s) {
        l[s] = pml[(long long)s * R + row];
        den += l[s];
    }
    float inv = (den > 0.f) ? 1.f / den : 0.f;
    int c0 = l31 * 4;
    float x[4] = {0.f, 0.f, 0.f, 0.f};
#pragma unroll
    for (int s = 0; s < SPLIT; ++s) {
        const __half* hp = pacc + ((long long)s * R + row) * 128 + c0;
        short4 h4 = *(const short4*)hp;
        const __half* hv = (const __half*)&h4;
        x[0] += l[s] * __half2float(hv[0]);
        x[1] += l[s] * __half2float(hv[1]);
        x[2] += l[s] * __half2float(hv[2]);
        x[3] += l[s] * __half2float(hv[3]);
    }
#pragma unroll
    for (int c = 0; c < 4; ++c) x[c] *= inv;
    float su = (x[0] + x[1]) + (x[2] + x[3]);
#pragma unroll
    for (int o = 1; o < 32; o <<= 1) su += __shfl_xor(su, o);
    float mu = su * (1.f / 128.f);
    float sq = 0.f;
#pragma unroll
    for (int c = 0; c < 4; ++c) { float d = x[c] - mu; sq += d * d; }
#pragma unroll
    for (int o = 1; o < 32; o <<= 1) sq += __shfl_xor(sq, o);
    float rstd = rsqrtf(sq * (1.f / 128.f) + 1e-5f);
    float4 xr = *(const float4*)(x1 + row * 128 + c0);
    float4 g4 = *(const float4*)(lng + c0);
    float4 b4 = *(const float4*)(lnb + c0);
    float4 o4;
    o4.x = (x[0] - mu) * rstd * g4.x + b4.x + xr.x;
    o4.y = (x[1] - mu) * rstd * g4.y + b4.y + xr.y;
    o4.z = (x[2] - mu) * rstd * g4.z + b4.z + xr.z;
    o4.w = (x[3] - mu) * rstd * g4.w + b4.w + xr.w;
    *(float4*)(out + row * 128 + c0) = o4;
}

// ---------------------------------------------------------------------------
extern "C" void kernel_launch(void* const* d_in, const int* in_sizes, int n_in,
                              void* d_out, int out_size, void* d_ws, size_t ws_size,
                              hipStream_t stream)
{
    const float* x1 = (const float*)d_in[0];
    const float* x2 = (const float*)d_in[1];
    const void* mask = d_in[2];
    const float* qw = (const float*)d_in[3];
    const float* qb = (const float*)d_in[4];
    const float* kw = (const float*)d_in[5];
    const float* kb = (const float*)d_in[6];
    const float* vw = (const float*)d_in[7];
    const float* vb = (const float*)d_in[8];
    const float* lng = (const float*)d_in[9];
    const float* lnb = (const float*)d_in[10];

    long long a = (long long)in_sizes[0] / 128;   // B*N
    long long c = (long long)in_sizes[1] / 128;   // B*M
    long long mm = (long long)in_sizes[2];        // B*N*M
    int B = (int)((a * c) / mm);
    int N = (int)(a / B);
    int M = (int)(c / B);
    long long R = a;

    char* p = (char*)d_ws;
    bf16* Q = (bf16*)p;    p += (size_t)a * 128 * sizeof(bf16);
    bf16* Kf = (bf16*)p;   p += (size_t)c * 128 * sizeof(bf16);
    bf16* Vf = (bf16*)p;   p += (size_t)c * 128 * sizeof(bf16);
    float* T = (float*)p;  p += 3 * 128 * 128 * sizeof(float);
    float* bt = (float*)p; p += 3 * 128 * sizeof(float);
    float* beff = (float*)p; p += 3 * 128 * sizeof(float);
    bf16* Weff = (bf16*)p; p += 3 * 128 * 128 * sizeof(bf16);
    int* flag = (int*)p;   p += 256;
    __half* pacc = (__half*)p; p += (size_t)SPLIT * R * 128 * sizeof(__half);
    float* pml = (float*)p;    p += (size_t)SPLIT * R * sizeof(float);

    compose_a<<<385, 128, 0, stream>>>(qw, qb, kw, kb, vw, vb,
                                       (const unsigned int*)mask, T, bt, flag);
    compose_b<<<384, 128, 0, stream>>>(qw, qb, kw, kb, vw, vb, T, bt, Weff, beff);

    proj_rm<<<(int)(a / 64), 256, 0, stream>>>(x1, Weff, beff, Q);
    proj_kvf<<<(int)(c / 64), 256, 0, stream>>>(x2, Weff + 16384, beff + 128,
                                                Weff + 2 * 16384, beff + 256, Kf, Vf, M);

    int nblk = B * (N / 64) * SPLIT;
    attn_split<<<nblk, 256, 0, stream>>>(Q, Kf, Vf, mask, flag, pacc, pml, B, N, M);
    combine<<<(int)(R / 8), 256, 0, stream>>>(pacc, pml, lng, lnb, x1, (float*)d_out, R);
}

// Round 18
// 156.928 us; speedup vs baseline: 1.0210x; 1.0048x over previous
//
#include <hip/hip_runtime.h>
#include <hip/hip_bf16.h>
#include <hip/hip_fp16.h>

typedef __hip_bfloat16 bf16;
typedef __attribute__((ext_vector_type(8))) short short8;
typedef __attribute__((ext_vector_type(4))) float f32x4;

#define MFMA(a, b, c) __builtin_amdgcn_mfma_f32_16x16x32_bf16((a), (b), (c), 0, 0, 0)
#define SPLIT 2

// ---------------------------------------------------------------------------
// compose_a + mask detection fused. Blocks 0..383: T = W2*W1, bt = W2*b1+b2.
// Block 384: mask element-size detection (flag=0 -> 4B elems, 1 -> bytes).
// ---------------------------------------------------------------------------
__global__ void compose_a(const float* __restrict__ qw, const float* __restrict__ qb,
                          const float* __restrict__ kw, const float* __restrict__ kb,
                          const float* __restrict__ vw, const float* __restrict__ vb,
                          const unsigned int* __restrict__ mask,
                          float* __restrict__ T, float* __restrict__ bt,
                          int* __restrict__ flag)
{
    if (blockIdx.x == 384) {
        __shared__ int bad;
        if (threadIdx.x == 0) bad = 0;
        __syncthreads();
        if (threadIdx.x < 256) {
            unsigned int w = mask[threadIdx.x];
            bool ok = (w == 0u) || (w == 1u) || (w == 0x3F800000u);
            if (!ok) atomicAdd(&bad, 1);
        }
        __syncthreads();
        if (threadIdx.x == 0) *flag = (bad == 0) ? 0 : 1;
        return;
    }
    int h = blockIdx.x >> 7;
    int i = blockIdx.x & 127;
    int j = threadIdx.x;
    const float* W = (h == 0) ? qw : (h == 1) ? kw : vw;
    const float* bv = (h == 0) ? qb : (h == 1) ? kb : vb;
    const float* W1 = W;
    const float* W2 = W + 128 * 128;
    float acc = 0.f;
    for (int k = 0; k < 128; ++k) acc += W2[i * 128 + k] * W1[k * 128 + j];
    T[h * 16384 + i * 128 + j] = acc;
    if (j == 0) {
        float bacc = 0.f;
        for (int k = 0; k < 128; ++k) bacc += W2[i * 128 + k] * bv[k];
        bt[h * 128 + i] = bacc + bv[128 + i];
    }
}

__global__ void compose_b(const float* __restrict__ qw, const float* __restrict__ qb,
                          const float* __restrict__ kw, const float* __restrict__ kb,
                          const float* __restrict__ vw, const float* __restrict__ vb,
                          const float* __restrict__ T, const float* __restrict__ bt,
                          bf16* __restrict__ Weff, float* __restrict__ beff)
{
    int h = blockIdx.x >> 7;
    int i = blockIdx.x & 127;
    int j = threadIdx.x;
    const float* W = (h == 0) ? qw : (h == 1) ? kw : vw;
    const float* bv = (h == 0) ? qb : (h == 1) ? kb : vb;
    const float* W3 = W + 2 * 128 * 128;
    const float* Th = T + h * 16384;
    float acc = 0.f;
    for (int k = 0; k < 128; ++k) acc += W3[i * 128 + k] * Th[k * 128 + j];
    float scale = (h == 0) ? (1.4426950408889634f * rsqrtf(128.0f)) : 1.0f;
    Weff[h * 16384 + i * 128 + j] = __float2bfloat16(acc * scale);
    if (j == 0) {
        float bacc = 0.f;
        for (int k = 0; k < 128; ++k) bacc += W3[i * 128 + k] * bt[h * 128 + k];
        beff[h * 128 + i] = (bacc + bv[256 + i]) * scale;
    }
}

// ---------------------------------------------------------------------------
// Q projection, row-major output: Y[r][w] = sum_c X[r][c]*W[w][c] + bias[w]
// ---------------------------------------------------------------------------
__global__ __launch_bounds__(256) void proj_rm(
    const float* __restrict__ X, const bf16* __restrict__ Wb,
    const float* __restrict__ bias, bf16* __restrict__ Y)
{
    __shared__ alignas(16) char sX[64 * 256];
    int tid = threadIdx.x;
    int lane = tid & 63, wave = tid >> 6;
    int l16 = lane & 15, lhi = lane >> 4;
    long long r0 = (long long)blockIdx.x * 64;
    {
        int row = tid >> 2, seg = tid & 3;
        const float4* src = reinterpret_cast<const float4*>(X + (r0 + row) * 128 + seg * 32);
        int swz = (row & 7) << 4;
        char* dst0 = &sX[0] + row * 256;
#pragma unroll
        for (int i = 0; i < 8; ++i) {
            float4 v = src[i];
            bf16* d = (bf16*)(dst0 + ((seg * 64 + i * 8) ^ swz));
            d[0] = __float2bfloat16(v.x); d[1] = __float2bfloat16(v.y);
            d[2] = __float2bfloat16(v.z); d[3] = __float2bfloat16(v.w);
        }
    }
    __syncthreads();
    int rloc = wave * 16 + l16;
    int swzr = (rloc & 7) << 4;
    short8 a[4];
#pragma unroll
    for (int c4 = 0; c4 < 4; ++c4)
        a[c4] = *(const short8*)(&sX[0] + ((rloc * 256 + lhi * 16 + c4 * 64) ^ swzr));
    f32x4 acc[8] = {};
#pragma unroll
    for (int n = 0; n < 8; ++n) {
        const bf16* wr = Wb + (n * 16 + l16) * 128 + lhi * 8;
#pragma unroll
        for (int c4 = 0; c4 < 4; ++c4)
            acc[n] = MFMA(a[c4], *(const short8*)(wr + c4 * 32), acc[n]);
    }
#pragma unroll
    for (int n = 0; n < 8; ++n) {
        float bia = bias[l16 + 16 * n];
#pragma unroll
        for (int r = 0; r < 4; ++r) {
            long long q = r0 + wave * 16 + lhi * 4 + r;
            Y[q * 128 + l16 + 16 * n] = __float2bfloat16(acc[n][r] + bia);
        }
    }
}

// ---------------------------------------------------------------------------
// FUSED K+V projection: one x2 LDS stage serves both heads. K emitted in
// QK^T B-fragment order, V in PV B-fragment order (coalesced 1KB bursts).
// ---------------------------------------------------------------------------
__global__ __launch_bounds__(256) void proj_kvf(
    const float* __restrict__ X2,
    const bf16* __restrict__ Wk, const float* __restrict__ bk,
    const bf16* __restrict__ Wv, const float* __restrict__ bv,
    bf16* __restrict__ Kf, bf16* __restrict__ Vf, int M)
{
    __shared__ alignas(16) char sX[64 * 256];     // staged x2 tile (swizzled bf16)
    __shared__ alignas(16) char rbuf[64 * 256];   // repack buffer
    int tid = threadIdx.x;
    int lane = tid & 63, wave = tid >> 6;
    int l16 = lane & 15, lhi = lane >> 4;
    long long r0 = (long long)blockIdx.x * 64;    // flattened (b*M + m0)
    int b = (int)(r0 / M);
    int m0 = (int)(r0 % M);
    {
        int row = tid >> 2, seg = tid & 3;
        const float4* src = reinterpret_cast<const float4*>(X2 + (r0 + row) * 128 + seg * 32);
        int swz = (row & 7) << 4;
        char* dst0 = &sX[0] + row * 256;
#pragma unroll
        for (int i = 0; i < 8; ++i) {
            float4 v = src[i];
            bf16* d = (bf16*)(dst0 + ((seg * 64 + i * 8) ^ swz));
            d[0] = __float2bfloat16(v.x); d[1] = __float2bfloat16(v.y);
            d[2] = __float2bfloat16(v.z); d[3] = __float2bfloat16(v.w);
        }
    }
    __syncthreads();

    // ---------------- K phase ----------------
    {
        int rloc = wave * 16 + l16;
        int swzr = (rloc & 7) << 4;
        short8 a[4];
#pragma unroll
        for (int c4 = 0; c4 < 4; ++c4)
            a[c4] = *(const short8*)(&sX[0] + ((rloc * 256 + lhi * 16 + c4 * 64) ^ swzr));
        f32x4 acc[8] = {};
#pragma unroll
        for (int n = 0; n < 8; ++n) {
            const bf16* wr = Wk + (n * 16 + l16) * 128 + lhi * 8;
#pragma unroll
            for (int c4 = 0; c4 < 4; ++c4)
                acc[n] = MFMA(a[c4], *(const short8*)(wr + c4 * 32), acc[n]);
        }
#pragma unroll
        for (int n = 0; n < 8; ++n) {
            float bia = bk[l16 + 16 * n];
#pragma unroll
            for (int r = 0; r < 4; ++r) {
                int row = wave * 16 + lhi * 4 + r;
                *(bf16*)(&rbuf[0] + ((row * 256 + (l16 + 16 * n) * 2) ^ ((row & 7) << 4))) =
                    __float2bfloat16(acc[n][r] + bia);
            }
        }
    }
    __syncthreads();
#pragma unroll
    for (int c4 = 0; c4 < 4; ++c4) {
        int row = wave * 16 + l16;
        short8 v = *(const short8*)(&rbuf[0] +
            ((row * 256 + c4 * 64 + lhi * 16) ^ ((row & 7) << 4)));
        long long tile = (r0 >> 4) + wave;
        *(short8*)(Kf + (tile * 4 + c4) * 512 + lane * 8) = v;
    }

    // ---------------- V phase (sX still intact) ----------------
    int w0 = wave * 32;
    short8 a2[2][4];
#pragma unroll
    for (int wt = 0; wt < 2; ++wt) {
        const bf16* wr = Wv + (w0 + wt * 16 + l16) * 128 + lhi * 8;
#pragma unroll
        for (int c4 = 0; c4 < 4; ++c4) a2[wt][c4] = *(const short8*)(wr + c4 * 32);
    }
    f32x4 acc2[2][4] = {};
#pragma unroll
    for (int mtl = 0; mtl < 4; ++mtl) {
        int rloc = mtl * 16 + l16;
        int swzr = (rloc & 7) << 4;
#pragma unroll
        for (int c4 = 0; c4 < 4; ++c4) {
            short8 xb = *(const short8*)(&sX[0] + ((rloc * 256 + lhi * 16 + c4 * 64) ^ swzr));
            acc2[0][mtl] = MFMA(a2[0][c4], xb, acc2[0][mtl]);
            acc2[1][mtl] = MFMA(a2[1][c4], xb, acc2[1][mtl]);
        }
    }
    __syncthreads();   // all Kf emission reads of rbuf done
#pragma unroll
    for (int wt = 0; wt < 2; ++wt) {
#pragma unroll
        for (int r = 0; r < 4; ++r) {
            int w = w0 + wt * 16 + lhi * 4 + r;
            float bia = bv[w];
#pragma unroll
            for (int mtl = 0; mtl < 4; ++mtl) {
                int mloc = mtl * 16 + l16;
                *(bf16*)(&rbuf[0] + ((w * 128 + mloc * 2) ^ ((w & 7) << 4))) =
                    __float2bfloat16(acc2[wt][mtl][r] + bia);
            }
        }
    }
    __syncthreads();
#pragma unroll
    for (int q = 0; q < 4; ++q) {
        int fr = wave * 4 + q;
        int gloc = fr >> 3, n = fr & 7;
        int row = n * 16 + l16;
        short8 v = *(const short8*)(&rbuf[0] +
            ((row * 128 + gloc * 64 + lhi * 16) ^ ((row & 7) << 4)));
        long long g = (long long)b * (M >> 5) + (m0 >> 5) + gloc;
        *(short8*)(Vf + (g * 8 + n) * 512 + lane * 8) = v;
    }
}

// ---------------------------------------------------------------------------
// Flash attention (R13 structure): KV-split=2, fixed-max softmax, swapped
// QK^T, K/V/mask double-buffered block-cooperative LDS staging, zero-LDS P
// redistribution. R18: CONFLICT-FREE FRAGMENT CHUNK PERMUTATION -- LDS frag
// accesses at lane*16 put lanes {i,i+8,..} in the same bank quad (8-way
// alias; SQ_LDS_BANK_CONFLICT readings of exactly 2^20/2^21 suggest counter
// saturation hid this). Chunk index sigma(lane) = lane ^ (lane>>3) is a
// bijection whose low-3 bits mix in the high bits -> all 8 lanes of each
// aliasing octet land in distinct bank quads. Applied identically on the
// staging-write and MFMA-read side, so placement/retrieval is invariant.
// NOTE (R4/R8): never raise waves/EU via launch_bounds (spill explosion).
// NOTE (R12): block-shared operands (K, V) stay in LDS.
// ---------------------------------------------------------------------------
__global__ __launch_bounds__(256, 4) void attn_split(
    const bf16* __restrict__ Q, const bf16* __restrict__ Kf, const bf16* __restrict__ Vf,
    const void* __restrict__ maskp, const int* __restrict__ flagp,
    __half* __restrict__ pacc, float* __restrict__ pml,
    int B, int N, int M)
{
    __shared__ alignas(16) char kbuf[2][8192];          // 32kv x 128ch bf16, frag order
    __shared__ alignas(16) char vbuf[2][8192];          // 8 frags x 1KB
    __shared__ alignas(16) unsigned char smask[4][512]; // per-wave 16q x 32kv mask bytes
    int nq = N >> 6;
    int nwg = gridDim.x;
    int bid = blockIdx.x;
    int wg = ((nwg & 7) == 0) ? ((bid & 7) * (nwg >> 3) + (bid >> 3)) : bid;
    int qt = wg % nq;
    int s  = (wg / nq) % SPLIT;
    int b  = wg / (nq * SPLIT);
    int tid = threadIdx.x;
    int lane = tid & 63, wave = tid >> 6;
    int l16 = lane & 15, lhi = lane >> 4;
    int q0 = qt * 64 + wave * 16;
    int Mh = M / SPLIT;
    int mbase = s * Mh;
    long long R = (long long)B * N;
    int fl4 = (*flagp == 0);
    const int NT = Mh >> 5;   // 32-kv tiles

    // conflict-free chunk slot: sigma(lane) = lane ^ (lane>>3), 16B granules
    int sl = ((lane ^ (lane >> 3)) & 63) * 16;

    const bf16* qptr = Q + ((long long)b * N + q0 + l16) * 128 + lhi * 8;
    short8 aq[4];
#pragma unroll
    for (int c4 = 0; c4 < 4; ++c4) aq[c4] = *(const short8*)(qptr + c4 * 32);

    long long ktile0 = ((long long)b * M + mbase) >> 4;   // 16-wide kv tiles
    long long gbase  = ((long long)b * M + mbase) >> 5;   // 32-wide kv groups

    int srow = lane >> 2, soff = (lane & 3) * 8;
    long long mrowb = ((long long)b * N + q0 + srow) * (long long)M + mbase + soff;

    unsigned char* smw = &smask[wave][0];

    f32x4 acc[8] = {};
    float plsum = 0.f;   // per-lane partial sum for q-row l16

    auto mload = [&](int t) -> uint2 {
        uint2 r;
        if (fl4) {
            const int* mp = (const int*)maskp;
            const int4* pp = (const int4*)(mp + mrowb + (long long)t * 32);
            int4 a = pp[0], bb = pp[1];
            r.x = (a.x ? 1u : 0u) | ((a.y ? 1u : 0u) << 8) |
                  ((a.z ? 1u : 0u) << 16) | ((a.w ? 1u : 0u) << 24);
            r.y = (bb.x ? 1u : 0u) | ((bb.y ? 1u : 0u) << 8) |
                  ((bb.z ? 1u : 0u) << 16) | ((bb.w ? 1u : 0u) << 24);
        } else {
            r = *(const uint2*)((const unsigned char*)maskp + mrowb + (long long)t * 32);
        }
        return r;
    };

    // ---- prologue: stage K/V tile 0 + mask tile 0 ----
    {
        long long F = ktile0 * 4 + wave * 2;
        long long G = gbase * 8 + wave * 2;
        int4 k0 = *(const int4*)(Kf + F * 512 + lane * 8);
        int4 k1 = *(const int4*)(Kf + (F + 1) * 512 + lane * 8);
        int4 v0 = *(const int4*)(Vf + G * 512 + lane * 8);
        int4 v1 = *(const int4*)(Vf + (G + 1) * 512 + lane * 8);
        uint2 mreg = mload(0);
        *(int4*)(&kbuf[0][(wave * 2 + 0) * 1024 + sl]) = k0;
        *(int4*)(&kbuf[0][(wave * 2 + 1) * 1024 + sl]) = k1;
        *(int4*)(&vbuf[0][(wave * 2 + 0) * 1024 + sl]) = v0;
        *(int4*)(&vbuf[0][(wave * 2 + 1) * 1024 + sl]) = v1;
        *(uint2*)(smw + srow * 32 + soff) = mreg;
        __syncthreads();
    }

    for (int t = 0; t < NT; ++t) {
        int cur = t & 1;
        // ---- 1. issue staging loads for tile t+1 (hide under this iter) ----
        int4 ks0, ks1, vs0, vs1;
        uint2 mreg;
        bool nxt = (t + 1 < NT);
        if (nxt) {
            long long F = (ktile0 + 2LL * (t + 1)) * 4 + wave * 2;
            long long G = (gbase + (t + 1)) * 8 + wave * 2;
            ks0 = *(const int4*)(Kf + F * 512 + lane * 8);
            ks1 = *(const int4*)(Kf + (F + 1) * 512 + lane * 8);
            vs0 = *(const int4*)(Vf + G * 512 + lane * 8);
            vs1 = *(const int4*)(Vf + (G + 1) * 512 + lane * 8);
            mreg = mload(t + 1);
        }

        // ---- 2. S^T = K Q^T from LDS (swapped operands, 8 MFMAs) ----
        __builtin_amdgcn_s_setprio(1);
        f32x4 sv[2];
#pragma unroll
        for (int j = 0; j < 2; ++j) {
            f32x4 tt = {0.f, 0.f, 0.f, 0.f};
#pragma unroll
            for (int c4 = 0; c4 < 4; ++c4)
                tt = MFMA(*(const short8*)(&kbuf[cur][(j * 4 + c4) * 1024 + sl]),
                          aq[c4], tt);
            sv[j] = tt;
        }
        __builtin_amdgcn_s_setprio(0);

        // ---- 3. lane-local softmax; pack kv-blocks B0 (a=g), B1 (a=g+4) ----
        uint2 Bb[2];
#pragma unroll
        for (int j = 0; j < 2; ++j) {
            unsigned int mk = *(const unsigned int*)(smw + l16 * 32 + 16 * j + lhi * 4);
            float p0 = (mk & 0x000000ffu) ? 0.f : exp2f(sv[j][0]);
            float p1 = (mk & 0x0000ff00u) ? 0.f : exp2f(sv[j][1]);
            float p2 = (mk & 0x00ff0000u) ? 0.f : exp2f(sv[j][2]);
            float p3 = (mk & 0xff000000u) ? 0.f : exp2f(sv[j][3]);
            plsum += (p0 + p1) + (p2 + p3);
            unsigned int w0, w1;
            asm("v_cvt_pk_bf16_f32 %0, %1, %2" : "=v"(w0) : "v"(p0), "v"(p1));
            asm("v_cvt_pk_bf16_f32 %0, %1, %2" : "=v"(w1) : "v"(p2), "v"(p3));
            Bb[j].x = w0; Bb[j].y = w1;
        }

        // ---- 4. in-register P redistribution (4x2 -> 2x4 block transpose) --
        uint2 X1 = (lhi < 2) ? Bb[1] : Bb[0];
        uint2 Qb;
        Qb.x = __shfl_xor((int)X1.x, 32);
        Qb.y = __shfl_xor((int)X1.y, 32);
        uint2 Pb = (lhi < 2) ? Bb[0] : Bb[1];
        uint2 X2 = (lhi == 1 || lhi == 2) ? Pb : Qb;
        uint2 Y2;
        Y2.x = __shfl_xor((int)X2.x, 16);
        Y2.y = __shfl_xor((int)X2.y, 16);
        uint2 s0 = (lhi == 0) ? Pb : (lhi == 1) ? Y2 : (lhi == 2) ? Qb : Y2;
        uint2 s1 = (lhi == 0) ? Y2 : (lhi == 1) ? Qb : (lhi == 2) ? Y2 : Pb;
        unsigned int paw[4] = {s0.x, s0.y, s1.x, s1.y};
        short8 pa = *(const short8*)paw;

        // ---- 5. O += P V from LDS (8 MFMAs) ----
        __builtin_amdgcn_s_setprio(1);
#pragma unroll
        for (int n = 0; n < 8; ++n)
            acc[n] = MFMA(pa, *(const short8*)(&vbuf[cur][n * 1024 + sl]), acc[n]);
        __builtin_amdgcn_s_setprio(0);

        // ---- 6. land staged tile t+1 into the other buffer; barrier ----
        if (nxt) {
            int nx = cur ^ 1;
            *(int4*)(&kbuf[nx][(wave * 2 + 0) * 1024 + sl]) = ks0;
            *(int4*)(&kbuf[nx][(wave * 2 + 1) * 1024 + sl]) = ks1;
            *(int4*)(&vbuf[nx][(wave * 2 + 0) * 1024 + sl]) = vs0;
            *(int4*)(&vbuf[nx][(wave * 2 + 1) * 1024 + sl]) = vs1;
            *(uint2*)(smw + srow * 32 + soff) = mreg;
            __syncthreads();
        }
    }

    // ---- epilogue: full row-sum across the 4 lhi lanes of q-row l16 ----
    float lsum = plsum;
    lsum += __shfl_xor(lsum, 16);
    lsum += __shfl_xor(lsum, 32);
    float invq = (lsum > 0.f) ? 1.f / lsum : 0.f;
    float inv[4];
#pragma unroll
    for (int r = 0; r < 4; ++r) inv[r] = __shfl(invq, lhi * 4 + r);
    long long rowg[4];
#pragma unroll
    for (int r = 0; r < 4; ++r) rowg[r] = (long long)b * N + q0 + lhi * 4 + r;
#pragma unroll
    for (int n = 0; n < 8; ++n)
#pragma unroll
        for (int r = 0; r < 4; ++r)
            pacc[((long long)s * R + rowg[r]) * 128 + l16 + 16 * n] =
                __float2half(acc[n][r] * inv[r]);
    if (lhi == 0)
        pml[(long long)s * R + (long long)b * N + q0 + l16] = lsum;
}

// ---------------------------------------------------------------------------
// Combine (vectorized): 2 rows per wave, 32 lanes/row x 4 channels.
// ---------------------------------------------------------------------------
__global__ __launch_bounds__(256) void combine(
    const __half* __restrict__ pacc, const float* __restrict__ pml,
    const float* __restrict__ lng, const float* __restrict__ lnb,
    const float* __restrict__ x1, float* __restrict__ out, long long R)
{
    int tid = threadIdx.x;
    int lane = tid & 63, wave = tid >> 6;
    int hi = lane >> 5, l31 = lane & 31;
    long long row = (long long)blockIdx.x * 8 + wave * 2 + hi;
    float l[SPLIT];
    float den = 0.f;
#pragma unroll
    for (int s = 0; s < SPLIT; ++s) {
        l[s] = pml[(long long)s * R + row];
        den += l[s];
    }
    float inv = (den > 0.f) ? 1.f / den : 0.f;
    int c0 = l31 * 4;
    float x[4] = {0.f, 0.f, 0.f, 0.f};
#pragma unroll
    for (int s = 0; s < SPLIT; ++s) {
        const __half* hp = pacc + ((long long)s * R + row) * 128 + c0;
        short4 h4 = *(const short4*)hp;
        const __half* hv = (const __half*)&h4;
        x[0] += l[s] * __half2float(hv[0]);
        x[1] += l[s] * __half2float(hv[1]);
        x[2] += l[s] * __half2float(hv[2]);
        x[3] += l[s] * __half2float(hv[3]);
    }
#pragma unroll
    for (int c = 0; c < 4; ++c) x[c] *= inv;
    float su = (x[0] + x[1]) + (x[2] + x[3]);
#pragma unroll
    for (int o = 1; o < 32; o <<= 1) su += __shfl_xor(su, o);
    float mu = su * (1.f / 128.f);
    float sq = 0.f;
#pragma unroll
    for (int c = 0; c < 4; ++c) { float d = x[c] - mu; sq += d * d; }
#pragma unroll
    for (int o = 1; o < 32; o <<= 1) sq += __shfl_xor(sq, o);
    float rstd = rsqrtf(sq * (1.f / 128.f) + 1e-5f);
    float4 xr = *(const float4*)(x1 + row * 128 + c0);
    float4 g4 = *(const float4*)(lng + c0);
    float4 b4 = *(const float4*)(lnb + c0);
    float4 o4;
    o4.x = (x[0] - mu) * rstd * g4.x + b4.x + xr.x;
    o4.y = (x[1] - mu) * rstd * g4.y + b4.y + xr.y;
    o4.z = (x[2] - mu) * rstd * g4.z + b4.z + xr.z;
    o4.w = (x[3] - mu) * rstd * g4.w + b4.w + xr.w;
    *(float4*)(out + row * 128 + c0) = o4;
}

// ---------------------------------------------------------------------------
extern "C" void kernel_launch(void* const* d_in, const int* in_sizes, int n_in,
                              void* d_out, int out_size, void* d_ws, size_t ws_size,
                              hipStream_t stream)
{
    const float* x1 = (const float*)d_in[0];
    const float* x2 = (const float*)d_in[1];
    const void* mask = d_in[2];
    const float* qw = (const float*)d_in[3];
    const float* qb = (const float*)d_in[4];
    const float* kw = (const float*)d_in[5];
    const float* kb = (const float*)d_in[6];
    const float* vw = (const float*)d_in[7];
    const float* vb = (const float*)d_in[8];
    const float* lng = (const float*)d_in[9];
    const float* lnb = (const float*)d_in[10];

    long long a = (long long)in_sizes[0] / 128;   // B*N
    long long c = (long long)in_sizes[1] / 128;   // B*M
    long long mm = (long long)in_sizes[2];        // B*N*M
    int B = (int)((a * c) / mm);
    int N = (int)(a / B);
    int M = (int)(c / B);
    long long R = a;

    char* p = (char*)d_ws;
    bf16* Q = (bf16*)p;    p += (size_t)a * 128 * sizeof(bf16);
    bf16* Kf = (bf16*)p;   p += (size_t)c * 128 * sizeof(bf16);
    bf16* Vf = (bf16*)p;   p += (size_t)c * 128 * sizeof(bf16);
    float* T = (float*)p;  p += 3 * 128 * 128 * sizeof(float);
    float* bt = (float*)p; p += 3 * 128 * sizeof(float);
    float* beff = (float*)p; p += 3 * 128 * sizeof(float);
    bf16* Weff = (bf16*)p; p += 3 * 128 * 128 * sizeof(bf16);
    int* flag = (int*)p;   p += 256;
    __half* pacc = (__half*)p; p += (size_t)SPLIT * R * 128 * sizeof(__half);
    float* pml = (float*)p;    p += (size_t)SPLIT * R * sizeof(float);

    compose_a<<<385, 128, 0, stream>>>(qw, qb, kw, kb, vw, vb,
                                       (const unsigned int*)mask, T, bt, flag);
    compose_b<<<384, 128, 0, stream>>>(qw, qb, kw, kb, vw, vb, T, bt, Weff, beff);

    proj_rm<<<(int)(a / 64), 256, 0, stream>>>(x1, Weff, beff, Q);
    proj_kvf<<<(int)(c / 64), 256, 0, stream>>>(x2, Weff + 16384, beff + 128,
                                                Weff + 2 * 16384, beff + 256, Kf, Vf, M);

    int nblk = B * (N / 64) * SPLIT;
    attn_split<<<nblk, 256, 0, stream>>>(Q, Kf, Vf, mask, flag, pacc, pml, B, N, M);
    combine<<<(int)(R / 8), 256, 0, stream>>>(pacc, pml, lng, lnb, x1, (float*)d_out, R);
}

// Round 19
// 153.856 us; speedup vs baseline: 1.0413x; 1.0200x over previous
//
#include <hip/hip_runtime.h>
#include <hip/hip_bf16.h>
#include <hip/hip_fp16.h>

typedef __hip_bfloat16 bf16;
typedef __attribute__((ext_vector_type(8))) short short8;
typedef __attribute__((ext_vector_type(4))) float f32x4;

#define MFMA(a, b, c) __builtin_amdgcn_mfma_f32_16x16x32_bf16((a), (b), (c), 0, 0, 0)
#define SPLIT 2
// direct HBM/L2 -> LDS staging, 16B per lane; LDS dest = uniform base + lane*16
#define GLOAD_LDS(gsrc, lbase)                                              \
    __builtin_amdgcn_global_load_lds(                                       \
        (const __attribute__((address_space(1))) void*)(gsrc),              \
        (__attribute__((address_space(3))) void*)(lbase), 16, 0, 0)

// ---------------------------------------------------------------------------
// compose_a + mask detection fused. Blocks 0..383: T = W2*W1, bt = W2*b1+b2.
// Block 384: mask element-size detection (flag=0 -> 4B elems, 1 -> bytes).
// ---------------------------------------------------------------------------
__global__ void compose_a(const float* __restrict__ qw, const float* __restrict__ qb,
                          const float* __restrict__ kw, const float* __restrict__ kb,
                          const float* __restrict__ vw, const float* __restrict__ vb,
                          const unsigned int* __restrict__ mask,
                          float* __restrict__ T, float* __restrict__ bt,
                          int* __restrict__ flag)
{
    if (blockIdx.x == 384) {
        __shared__ int bad;
        if (threadIdx.x == 0) bad = 0;
        __syncthreads();
        if (threadIdx.x < 256) {
            unsigned int w = mask[threadIdx.x];
            bool ok = (w == 0u) || (w == 1u) || (w == 0x3F800000u);
            if (!ok) atomicAdd(&bad, 1);
        }
        __syncthreads();
        if (threadIdx.x == 0) *flag = (bad == 0) ? 0 : 1;
        return;
    }
    int h = blockIdx.x >> 7;
    int i = blockIdx.x & 127;
    int j = threadIdx.x;
    const float* W = (h == 0) ? qw : (h == 1) ? kw : vw;
    const float* bv = (h == 0) ? qb : (h == 1) ? kb : vb;
    const float* W1 = W;
    const float* W2 = W + 128 * 128;
    float acc = 0.f;
    for (int k = 0; k < 128; ++k) acc += W2[i * 128 + k] * W1[k * 128 + j];
    T[h * 16384 + i * 128 + j] = acc;
    if (j == 0) {
        float bacc = 0.f;
        for (int k = 0; k < 128; ++k) bacc += W2[i * 128 + k] * bv[k];
        bt[h * 128 + i] = bacc + bv[128 + i];
    }
}

__global__ void compose_b(const float* __restrict__ qw, const float* __restrict__ qb,
                          const float* __restrict__ kw, const float* __restrict__ kb,
                          const float* __restrict__ vw, const float* __restrict__ vb,
                          const float* __restrict__ T, const float* __restrict__ bt,
                          bf16* __restrict__ Weff, float* __restrict__ beff)
{
    int h = blockIdx.x >> 7;
    int i = blockIdx.x & 127;
    int j = threadIdx.x;
    const float* W = (h == 0) ? qw : (h == 1) ? kw : vw;
    const float* bv = (h == 0) ? qb : (h == 1) ? kb : vb;
    const float* W3 = W + 2 * 128 * 128;
    const float* Th = T + h * 16384;
    float acc = 0.f;
    for (int k = 0; k < 128; ++k) acc += W3[i * 128 + k] * Th[k * 128 + j];
    float scale = (h == 0) ? (1.4426950408889634f * rsqrtf(128.0f)) : 1.0f;
    Weff[h * 16384 + i * 128 + j] = __float2bfloat16(acc * scale);
    if (j == 0) {
        float bacc = 0.f;
        for (int k = 0; k < 128; ++k) bacc += W3[i * 128 + k] * bt[h * 128 + k];
        beff[h * 128 + i] = (bacc + bv[256 + i]) * scale;
    }
}

// ---------------------------------------------------------------------------
// Q projection, row-major output: Y[r][w] = sum_c X[r][c]*W[w][c] + bias[w]
// ---------------------------------------------------------------------------
__global__ __launch_bounds__(256) void proj_rm(
    const float* __restrict__ X, const bf16* __restrict__ Wb,
    const float* __restrict__ bias, bf16* __restrict__ Y)
{
    __shared__ alignas(16) char sX[64 * 256];
    int tid = threadIdx.x;
    int lane = tid & 63, wave = tid >> 6;
    int l16 = lane & 15, lhi = lane >> 4;
    long long r0 = (long long)blockIdx.x * 64;
    {
        int row = tid >> 2, seg = tid & 3;
        const float4* src = reinterpret_cast<const float4*>(X + (r0 + row) * 128 + seg * 32);
        int swz = (row & 7) << 4;
        char* dst0 = &sX[0] + row * 256;
#pragma unroll
        for (int i = 0; i < 8; ++i) {
            float4 v = src[i];
            bf16* d = (bf16*)(dst0 + ((seg * 64 + i * 8) ^ swz));
            d[0] = __float2bfloat16(v.x); d[1] = __float2bfloat16(v.y);
            d[2] = __float2bfloat16(v.z); d[3] = __float2bfloat16(v.w);
        }
    }
    __syncthreads();
    int rloc = wave * 16 + l16;
    int swzr = (rloc & 7) << 4;
    short8 a[4];
#pragma unroll
    for (int c4 = 0; c4 < 4; ++c4)
        a[c4] = *(const short8*)(&sX[0] + ((rloc * 256 + lhi * 16 + c4 * 64) ^ swzr));
    f32x4 acc[8] = {};
#pragma unroll
    for (int n = 0; n < 8; ++n) {
        const bf16* wr = Wb + (n * 16 + l16) * 128 + lhi * 8;
#pragma unroll
        for (int c4 = 0; c4 < 4; ++c4)
            acc[n] = MFMA(a[c4], *(const short8*)(wr + c4 * 32), acc[n]);
    }
#pragma unroll
    for (int n = 0; n < 8; ++n) {
        float bia = bias[l16 + 16 * n];
#pragma unroll
        for (int r = 0; r < 4; ++r) {
            long long q = r0 + wave * 16 + lhi * 4 + r;
            Y[q * 128 + l16 + 16 * n] = __float2bfloat16(acc[n][r] + bia);
        }
    }
}

// ---------------------------------------------------------------------------
// FUSED K+V projection: one x2 LDS stage serves both heads. K emitted in
// QK^T B-fragment order, V in PV B-fragment order (coalesced 1KB bursts).
// ---------------------------------------------------------------------------
__global__ __launch_bounds__(256) void proj_kvf(
    const float* __restrict__ X2,
    const bf16* __restrict__ Wk, const float* __restrict__ bk,
    const bf16* __restrict__ Wv, const float* __restrict__ bv,
    bf16* __restrict__ Kf, bf16* __restrict__ Vf, int M)
{
    __shared__ alignas(16) char sX[64 * 256];     // staged x2 tile (swizzled bf16)
    __shared__ alignas(16) char rbuf[64 * 256];   // repack buffer
    int tid = threadIdx.x;
    int lane = tid & 63, wave = tid >> 6;
    int l16 = lane & 15, lhi = lane >> 4;
    long long r0 = (long long)blockIdx.x * 64;    // flattened (b*M + m0)
    int b = (int)(r0 / M);
    int m0 = (int)(r0 % M);
    {
        int row = tid >> 2, seg = tid & 3;
        const float4* src = reinterpret_cast<const float4*>(X2 + (r0 + row) * 128 + seg * 32);
        int swz = (row & 7) << 4;
        char* dst0 = &sX[0] + row * 256;
#pragma unroll
        for (int i = 0; i < 8; ++i) {
            float4 v = src[i];
            bf16* d = (bf16*)(dst0 + ((seg * 64 + i * 8) ^ swz));
            d[0] = __float2bfloat16(v.x); d[1] = __float2bfloat16(v.y);
            d[2] = __float2bfloat16(v.z); d[3] = __float2bfloat16(v.w);
        }
    }
    __syncthreads();

    // ---------------- K phase ----------------
    {
        int rloc = wave * 16 + l16;
        int swzr = (rloc & 7) << 4;
        short8 a[4];
#pragma unroll
        for (int c4 = 0; c4 < 4; ++c4)
            a[c4] = *(const short8*)(&sX[0] + ((rloc * 256 + lhi * 16 + c4 * 64) ^ swzr));
        f32x4 acc[8] = {};
#pragma unroll
        for (int n = 0; n < 8; ++n) {
            const bf16* wr = Wk + (n * 16 + l16) * 128 + lhi * 8;
#pragma unroll
            for (int c4 = 0; c4 < 4; ++c4)
                acc[n] = MFMA(a[c4], *(const short8*)(wr + c4 * 32), acc[n]);
        }
#pragma unroll
        for (int n = 0; n < 8; ++n) {
            float bia = bk[l16 + 16 * n];
#pragma unroll
            for (int r = 0; r < 4; ++r) {
                int row = wave * 16 + lhi * 4 + r;
                *(bf16*)(&rbuf[0] + ((row * 256 + (l16 + 16 * n) * 2) ^ ((row & 7) << 4))) =
                    __float2bfloat16(acc[n][r] + bia);
            }
        }
    }
    __syncthreads();
#pragma unroll
    for (int c4 = 0; c4 < 4; ++c4) {
        int row = wave * 16 + l16;
        short8 v = *(const short8*)(&rbuf[0] +
            ((row * 256 + c4 * 64 + lhi * 16) ^ ((row & 7) << 4)));
        long long tile = (r0 >> 4) + wave;
        *(short8*)(Kf + (tile * 4 + c4) * 512 + lane * 8) = v;
    }

    // ---------------- V phase (sX still intact) ----------------
    int w0 = wave * 32;
    short8 a2[2][4];
#pragma unroll
    for (int wt = 0; wt < 2; ++wt) {
        const bf16* wr = Wv + (w0 + wt * 16 + l16) * 128 + lhi * 8;
#pragma unroll
        for (int c4 = 0; c4 < 4; ++c4) a2[wt][c4] = *(const short8*)(wr + c4 * 32);
    }
    f32x4 acc2[2][4] = {};
#pragma unroll
    for (int mtl = 0; mtl < 4; ++mtl) {
        int rloc = mtl * 16 + l16;
        int swzr = (rloc & 7) << 4;
#pragma unroll
        for (int c4 = 0; c4 < 4; ++c4) {
            short8 xb = *(const short8*)(&sX[0] + ((rloc * 256 + lhi * 16 + c4 * 64) ^ swzr));
            acc2[0][mtl] = MFMA(a2[0][c4], xb, acc2[0][mtl]);
            acc2[1][mtl] = MFMA(a2[1][c4], xb, acc2[1][mtl]);
        }
    }
    __syncthreads();   // all Kf emission reads of rbuf done
#pragma unroll
    for (int wt = 0; wt < 2; ++wt) {
#pragma unroll
        for (int r = 0; r < 4; ++r) {
            int w = w0 + wt * 16 + lhi * 4 + r;
            float bia = bv[w];
#pragma unroll
            for (int mtl = 0; mtl < 4; ++mtl) {
                int mloc = mtl * 16 + l16;
                *(bf16*)(&rbuf[0] + ((w * 128 + mloc * 2) ^ ((w & 7) << 4))) =
                    __float2bfloat16(acc2[wt][mtl][r] + bia);
            }
        }
    }
    __syncthreads();
#pragma unroll
    for (int q = 0; q < 4; ++q) {
        int fr = wave * 4 + q;
        int gloc = fr >> 3, n = fr & 7;
        int row = n * 16 + l16;
        short8 v = *(const short8*)(&rbuf[0] +
            ((row * 128 + gloc * 64 + lhi * 16) ^ ((row & 7) << 4)));
        long long g = (long long)b * (M >> 5) + (m0 >> 5) + gloc;
        *(short8*)(Vf + (g * 8 + n) * 512 + lane * 8) = v;
    }
}

// ---------------------------------------------------------------------------
// Flash attention (R13 structure): KV-split=2, fixed-max softmax, swapped
// QK^T, zero-LDS P redistribution, double-buffered K/V staging.
// R19: K/V staging now uses __builtin_amdgcn_global_load_lds (16B/lane,
// LDS dest = wave-uniform base + lane*16, exactly our linear layout) --
// removes the VGPR round-trip, 4 ds_writes/wave/iter, ~16 held registers,
// and staging address VALU. The pre-barrier vmcnt(0) drains the DMA, giving
// the same full-iteration latency shadow. Linear lane*16 chunks on both
// sides (R18's sigma permutation reverted: proven neutral, and gload_lds
// requires the linear pattern -- both-sides-or-neither).
// NOTE (R4/R8): never raise waves/EU via launch_bounds (spill explosion).
// NOTE (R12): block-shared operands (K, V) stay in LDS.
// ---------------------------------------------------------------------------
__global__ __launch_bounds__(256, 4) void attn_split(
    const bf16* __restrict__ Q, const bf16* __restrict__ Kf, const bf16* __restrict__ Vf,
    const void* __restrict__ maskp, const int* __restrict__ flagp,
    __half* __restrict__ pacc, float* __restrict__ pml,
    int B, int N, int M)
{
    __shared__ alignas(16) char kbuf[2][8192];          // 32kv x 128ch bf16, frag order
    __shared__ alignas(16) char vbuf[2][8192];          // 8 frags x 1KB
    __shared__ alignas(16) unsigned char smask[4][512]; // per-wave 16q x 32kv mask bytes
    int nq = N >> 6;
    int nwg = gridDim.x;
    int bid = blockIdx.x;
    int wg = ((nwg & 7) == 0) ? ((bid & 7) * (nwg >> 3) + (bid >> 3)) : bid;
    int qt = wg % nq;
    int s  = (wg / nq) % SPLIT;
    int b  = wg / (nq * SPLIT);
    int tid = threadIdx.x;
    int lane = tid & 63, wave = tid >> 6;
    int l16 = lane & 15, lhi = lane >> 4;
    int q0 = qt * 64 + wave * 16;
    int Mh = M / SPLIT;
    int mbase = s * Mh;
    long long R = (long long)B * N;
    int fl4 = (*flagp == 0);
    const int NT = Mh >> 5;   // 32-kv tiles

    const bf16* qptr = Q + ((long long)b * N + q0 + l16) * 128 + lhi * 8;
    short8 aq[4];
#pragma unroll
    for (int c4 = 0; c4 < 4; ++c4) aq[c4] = *(const short8*)(qptr + c4 * 32);

    long long ktile0 = ((long long)b * M + mbase) >> 4;   // 16-wide kv tiles
    long long gbase  = ((long long)b * M + mbase) >> 5;   // 32-wide kv groups

    int srow = lane >> 2, soff = (lane & 3) * 8;
    long long mrowb = ((long long)b * N + q0 + srow) * (long long)M + mbase + soff;

    unsigned char* smw = &smask[wave][0];

    f32x4 acc[8] = {};
    float plsum = 0.f;   // per-lane partial sum for q-row l16

    auto mload = [&](int t) -> uint2 {
        uint2 r;
        if (fl4) {
            const int* mp = (const int*)maskp;
            const int4* pp = (const int4*)(mp + mrowb + (long long)t * 32);
            int4 a = pp[0], bb = pp[1];
            r.x = (a.x ? 1u : 0u) | ((a.y ? 1u : 0u) << 8) |
                  ((a.z ? 1u : 0u) << 16) | ((a.w ? 1u : 0u) << 24);
            r.y = (bb.x ? 1u : 0u) | ((bb.y ? 1u : 0u) << 8) |
                  ((bb.z ? 1u : 0u) << 16) | ((bb.w ? 1u : 0u) << 24);
        } else {
            r = *(const uint2*)((const unsigned char*)maskp + mrowb + (long long)t * 32);
        }
        return r;
    };

    // stage K/V tile t into LDS buffer bi via direct global->LDS DMA
    auto stageKV = [&](int t, int bi) {
        long long F = (ktile0 + 2LL * t) * 4 + wave * 2;
        long long G = (gbase + t) * 8 + wave * 2;
        GLOAD_LDS(Kf + F * 512 + lane * 8,       &kbuf[bi][(wave * 2 + 0) * 1024]);
        GLOAD_LDS(Kf + (F + 1) * 512 + lane * 8, &kbuf[bi][(wave * 2 + 1) * 1024]);
        GLOAD_LDS(Vf + G * 512 + lane * 8,       &vbuf[bi][(wave * 2 + 0) * 1024]);
        GLOAD_LDS(Vf + (G + 1) * 512 + lane * 8, &vbuf[bi][(wave * 2 + 1) * 1024]);
    };

    // ---- prologue: stage K/V tile 0 + mask tile 0 ----
    {
        stageKV(0, 0);
        uint2 mreg = mload(0);
        *(uint2*)(smw + srow * 32 + soff) = mreg;
        __syncthreads();   // vmcnt(0) drains the DMA before reads
    }

    for (int t = 0; t < NT; ++t) {
        int cur = t & 1;
        // ---- 1. issue DMA staging for tile t+1 into buf[cur^1] (safe: all
        //         reads of buf[cur^1] completed before the t-1 barrier) ----
        uint2 mreg;
        bool nxt = (t + 1 < NT);
        if (nxt) {
            stageKV(t + 1, cur ^ 1);
            mreg = mload(t + 1);
        }

        // ---- 2. S^T = K Q^T from LDS (swapped operands, 8 MFMAs) ----
        __builtin_amdgcn_s_setprio(1);
        f32x4 sv[2];
#pragma unroll
        for (int j = 0; j < 2; ++j) {
            f32x4 tt = {0.f, 0.f, 0.f, 0.f};
#pragma unroll
            for (int c4 = 0; c4 < 4; ++c4)
                tt = MFMA(*(const short8*)(&kbuf[cur][(j * 4 + c4) * 1024 + lane * 16]),
                          aq[c4], tt);
            sv[j] = tt;
        }
        __builtin_amdgcn_s_setprio(0);

        // ---- 3. lane-local softmax; pack kv-blocks B0 (a=g), B1 (a=g+4) ----
        uint2 Bb[2];
#pragma unroll
        for (int j = 0; j < 2; ++j) {
            unsigned int mk = *(const unsigned int*)(smw + l16 * 32 + 16 * j + lhi * 4);
            float p0 = (mk & 0x000000ffu) ? 0.f : exp2f(sv[j][0]);
            float p1 = (mk & 0x0000ff00u) ? 0.f : exp2f(sv[j][1]);
            float p2 = (mk & 0x00ff0000u) ? 0.f : exp2f(sv[j][2]);
            float p3 = (mk & 0xff000000u) ? 0.f : exp2f(sv[j][3]);
            plsum += (p0 + p1) + (p2 + p3);
            unsigned int w0, w1;
            asm("v_cvt_pk_bf16_f32 %0, %1, %2" : "=v"(w0) : "v"(p0), "v"(p1));
            asm("v_cvt_pk_bf16_f32 %0, %1, %2" : "=v"(w1) : "v"(p2), "v"(p3));
            Bb[j].x = w0; Bb[j].y = w1;
        }

        // ---- 4. in-register P redistribution (4x2 -> 2x4 block transpose) --
        uint2 X1 = (lhi < 2) ? Bb[1] : Bb[0];
        uint2 Qb;
        Qb.x = __shfl_xor((int)X1.x, 32);
        Qb.y = __shfl_xor((int)X1.y, 32);
        uint2 Pb = (lhi < 2) ? Bb[0] : Bb[1];
        uint2 X2 = (lhi == 1 || lhi == 2) ? Pb : Qb;
        uint2 Y2;
        Y2.x = __shfl_xor((int)X2.x, 16);
        Y2.y = __shfl_xor((int)X2.y, 16);
        uint2 s0 = (lhi == 0) ? Pb : (lhi == 1) ? Y2 : (lhi == 2) ? Qb : Y2;
        uint2 s1 = (lhi == 0) ? Y2 : (lhi == 1) ? Qb : (lhi == 2) ? Y2 : Pb;
        unsigned int paw[4] = {s0.x, s0.y, s1.x, s1.y};
        short8 pa = *(const short8*)paw;

        // ---- 5. O += P V from LDS (8 MFMAs) ----
        __builtin_amdgcn_s_setprio(1);
#pragma unroll
        for (int n = 0; n < 8; ++n)
            acc[n] = MFMA(pa, *(const short8*)(&vbuf[cur][n * 1024 + lane * 16]), acc[n]);
        __builtin_amdgcn_s_setprio(0);

        // ---- 6. land mask tile t+1; barrier drains the K/V DMA ----
        if (nxt) {
            *(uint2*)(smw + srow * 32 + soff) = mreg;
            __syncthreads();
        }
    }

    // ---- epilogue: full row-sum across the 4 lhi lanes of q-row l16 ----
    float lsum = plsum;
    lsum += __shfl_xor(lsum, 16);
    lsum += __shfl_xor(lsum, 32);
    float invq = (lsum > 0.f) ? 1.f / lsum : 0.f;
    float inv[4];
#pragma unroll
    for (int r = 0; r < 4; ++r) inv[r] = __shfl(invq, lhi * 4 + r);
    long long rowg[4];
#pragma unroll
    for (int r = 0; r < 4; ++r) rowg[r] = (long long)b * N + q0 + lhi * 4 + r;
#pragma unroll
    for (int n = 0; n < 8; ++n)
#pragma unroll
        for (int r = 0; r < 4; ++r)
            pacc[((long long)s * R + rowg[r]) * 128 + l16 + 16 * n] =
                __float2half(acc[n][r] * inv[r]);
    if (lhi == 0)
        pml[(long long)s * R + (long long)b * N + q0 + l16] = lsum;
}

// ---------------------------------------------------------------------------
// Combine (vectorized): 2 rows per wave, 32 lanes/row x 4 channels.
// ---------------------------------------------------------------------------
__global__ __launch_bounds__(256) void combine(
    const __half* __restrict__ pacc, const float* __restrict__ pml,
    const float* __restrict__ lng, const float* __restrict__ lnb,
    const float* __restrict__ x1, float* __restrict__ out, long long R)
{
    int tid = threadIdx.x;
    int lane = tid & 63, wave = tid >> 6;
    int hi = lane >> 5, l31 = lane & 31;
    long long row = (long long)blockIdx.x * 8 + wave * 2 + hi;
    float l[SPLIT];
    float den = 0.f;
#pragma unroll
    for (int s = 0; s < SPLIT; ++s) {
        l[s] = pml[(long long)s * R + row];
        den += l[s];
    }
    float inv = (den > 0.f) ? 1.f / den : 0.f;
    int c0 = l31 * 4;
    float x[4] = {0.f, 0.f, 0.f, 0.f};
#pragma unroll
    for (int s = 0; s < SPLIT; ++s) {
        const __half* hp = pacc + ((long long)s * R + row) * 128 + c0;
        short4 h4 = *(const short4*)hp;
        const __half* hv = (const __half*)&h4;
        x[0] += l[s] * __half2float(hv[0]);
        x[1] += l[s] * __half2float(hv[1]);
        x[2] += l[s] * __half2float(hv[2]);
        x[3] += l[s] * __half2float(hv[3]);
    }
#pragma unroll
    for (int c = 0; c < 4; ++c) x[c] *= inv;
    float su = (x[0] + x[1]) + (x[2] + x[3]);
#pragma unroll
    for (int o = 1; o < 32; o <<= 1) su += __shfl_xor(su, o);
    float mu = su * (1.f / 128.f);
    float sq = 0.f;
#pragma unroll
    for (int c = 0; c < 4; ++c) { float d = x[c] - mu; sq += d * d; }
#pragma unroll
    for (int o = 1; o < 32; o <<= 1) sq += __shfl_xor(sq, o);
    float rstd = rsqrtf(sq * (1.f / 128.f) + 1e-5f);
    float4 xr = *(const float4*)(x1 + row * 128 + c0);
    float4 g4 = *(const float4*)(lng + c0);
    float4 b4 = *(const float4*)(lnb + c0);
    float4 o4;
    o4.x = (x[0] - mu) * rstd * g4.x + b4.x + xr.x;
    o4.y = (x[1] - mu) * rstd * g4.y + b4.y + xr.y;
    o4.z = (x[2] - mu) * rstd * g4.z + b4.z + xr.z;
    o4.w = (x[3] - mu) * rstd * g4.w + b4.w + xr.w;
    *(float4*)(out + row * 128 + c0) = o4;
}

// ---------------------------------------------------------------------------
extern "C" void kernel_launch(void* const* d_in, const int* in_sizes, int n_in,
                              void* d_out, int out_size, void* d_ws, size_t ws_size,
                              hipStream_t stream)
{
    const float* x1 = (const float*)d_in[0];
    const float* x2 = (const float*)d_in[1];
    const void* mask = d_in[2];
    const float* qw = (const float*)d_in[3];
    const float* qb = (const float*)d_in[4];
    const float* kw = (const float*)d_in[5];
    const float* kb = (const float*)d_in[6];
    const float* vw = (const float*)d_in[7];
    const float* vb = (const float*)d_in[8];
    const float* lng = (const float*)d_in[9];
    const float* lnb = (const float*)d_in[10];

    long long a = (long long)in_sizes[0] / 128;   // B*N
    long long c = (long long)in_sizes[1] / 128;   // B*M
    long long mm = (long long)in_sizes[2];        // B*N*M
    int B = (int)((a * c) / mm);
    int N = (int)(a / B);
    int M = (int)(c / B);
    long long R = a;

    char* p = (char*)d_ws;
    bf16* Q = (bf16*)p;    p += (size_t)a * 128 * sizeof(bf16);
    bf16* Kf = (bf16*)p;   p += (size_t)c * 128 * sizeof(bf16);
    bf16* Vf = (bf16*)p;   p += (size_t)c * 128 * sizeof(bf16);
    float* T = (float*)p;  p += 3 * 128 * 128 * sizeof(float);
    float* bt = (float*)p; p += 3 * 128 * sizeof(float);
    float* beff = (float*)p; p += 3 * 128 * sizeof(float);
    bf16* Weff = (bf16*)p; p += 3 * 128 * 128 * sizeof(bf16);
    int* flag = (int*)p;   p += 256;
    __half* pacc = (__half*)p; p += (size_t)SPLIT * R * 128 * sizeof(__half);
    float* pml = (float*)p;    p += (size_t)SPLIT * R * sizeof(float);

    compose_a<<<385, 128, 0, stream>>>(qw, qb, kw, kb, vw, vb,
                                       (const unsigned int*)mask, T, bt, flag);
    compose_b<<<384, 128, 0, stream>>>(qw, qb, kw, kb, vw, vb, T, bt, Weff, beff);

    proj_rm<<<(int)(a / 64), 256, 0, stream>>>(x1, Weff, beff, Q);
    proj_kvf<<<(int)(c / 64), 256, 0, stream>>>(x2, Weff + 16384, beff + 128,
                                                Weff + 2 * 16384, beff + 256, Kf, Vf, M);

    int nblk = B * (N / 64) * SPLIT;
    attn_split<<<nblk, 256, 0, stream>>>(Q, Kf, Vf, mask, flag, pacc, pml, B, N, M);
    combine<<<(int)(R / 8), 256, 0, stream>>>(pacc, pml, lng, lnb, x1, (float*)d_out, R);
}